// Round 1
// baseline (1016.851 us; speedup 1.0000x reference)
//
#include <hip/hip_runtime.h>

#define NB 16
#define NN 300000
#define PRE 2000
#define POST 1000

typedef unsigned long long ull;

// ---------- workspace layout (bytes) ----------
static const size_t OFF_HIST1   = 0;                       // 16*1024*4 = 65536
static const size_t OFF_HIST2   = 65536;                   // 16*2048*4 = 131072
static const size_t OFF_HIST3   = 196608;                  // 131072
static const size_t OFF_CANDCNT = 327680;                  // 64 (pad 256)
static const size_t OFF_EQCNT   = 327936;                  // 64 (pad 256)
static const size_t OFF_BITMAP  = 328192;                  // 16*32*8 = 4096
static const size_t OFF_B1      = 332288;
static const size_t OFF_NEED1   = 332544;
static const size_t OFF_B2      = 332800;
static const size_t OFF_NEED2   = 333056;
static const size_t OFF_B3      = 333312;
static const size_t OFF_NEED3   = 333568;
static const size_t ZERO_BYTES  = 333824;                  // memset region
static const size_t OFF_CAND    = 333824;                  // 16*2048*4 = 131072
static const size_t OFF_EQBUF   = 464896;                  // 16*8192*4 = 524288
static const size_t OFF_BOXTMP  = 989184;                  // 16*2000*16 = 512000
static const size_t OFF_KEYS    = 1501184;                 // 16*2048*8 = 262144
static const size_t OFF_SORTED  = 1763328;                 // 512000
static const size_t OFF_NVALID  = 2275328;                 // 64 (pad 256)
static const size_t OFF_MASK    = 2275584;                 // 16*2000*32*8 = 8192000

__device__ __forceinline__ unsigned f2u(float f){
  unsigned b = __float_as_uint(f);
  return (b & 0x80000000u) ? ~b : (b | 0x80000000u);
}

// ---------- pass 1 histogram: top 10 bits ----------
__global__ void k_hist1(const float* __restrict__ cls, unsigned* __restrict__ hist){
  __shared__ unsigned h[1024];
  int img = blockIdx.y;
  for (int i = threadIdx.x; i < 1024; i += blockDim.x) h[i] = 0;
  __syncthreads();
  const float* p = cls + (size_t)img * NN;
  int stride = gridDim.x * blockDim.x;
  for (int i = blockIdx.x * blockDim.x + threadIdx.x; i < NN; i += stride)
    atomicAdd(&h[f2u(p[i]) >> 22], 1u);
  __syncthreads();
  unsigned* g = hist + img * 1024;
  for (int i = threadIdx.x; i < 1024; i += blockDim.x){
    unsigned v = h[i];
    if (v) atomicAdd(&g[i], v);
  }
}

// ---------- generic descending rank-select over a histogram ----------
__global__ void k_scan(const unsigned* __restrict__ hist, int bins,
                       const unsigned* __restrict__ tgt, unsigned K0,
                       unsigned* __restrict__ outBin, unsigned* __restrict__ outNeed){
  int img = blockIdx.x;
  int t = threadIdx.x;
  const unsigned* hh = hist + img * bins;
  unsigned K = tgt ? tgt[img] : K0;
  int per = bins >> 8;
  unsigned s = 0;
  for (int q = 0; q < per; q++) s += hh[bins - 1 - (t * per + q)];
  __shared__ unsigned arr[256];
  arr[t] = s;
  __syncthreads();
  for (int off = 1; off < 256; off <<= 1){
    unsigned v = (t >= off) ? arr[t - off] : 0u;
    __syncthreads();
    arr[t] += v;
    __syncthreads();
  }
  unsigned incl = arr[t], excl = incl - s;
  if (excl < K && K <= incl){
    unsigned c = excl;
    for (int q = 0; q < per; q++){
      int b = bins - 1 - (t * per + q);
      unsigned cnt = hh[b];
      if (c + cnt >= K){ outBin[img] = (unsigned)b; outNeed[img] = K - c; break; }
      c += cnt;
    }
  }
}

// ---------- pass 2 histogram: bits 21..11 within bin b1 ----------
__global__ void k_hist2(const float* __restrict__ cls, const unsigned* __restrict__ b1,
                        unsigned* __restrict__ hist){
  int img = blockIdx.y;
  unsigned bb1 = b1[img];
  const float* p = cls + (size_t)img * NN;
  unsigned* g = hist + img * 2048;
  int stride = gridDim.x * blockDim.x;
  for (int i = blockIdx.x * blockDim.x + threadIdx.x; i < NN; i += stride){
    unsigned u = f2u(p[i]);
    if ((u >> 22) == bb1) atomicAdd(&g[(u >> 11) & 0x7FFu], 1u);
  }
}

// ---------- pass 3 histogram: bits 10..0 within (b1,b2) ----------
__global__ void k_hist3(const float* __restrict__ cls, const unsigned* __restrict__ b1,
                        const unsigned* __restrict__ b2, unsigned* __restrict__ hist){
  int img = blockIdx.y;
  unsigned pref = (b1[img] << 11) | b2[img];
  const float* p = cls + (size_t)img * NN;
  unsigned* g = hist + img * 2048;
  int stride = gridDim.x * blockDim.x;
  for (int i = blockIdx.x * blockDim.x + threadIdx.x; i < NN; i += stride){
    unsigned u = f2u(p[i]);
    if ((u >> 11) == pref) atomicAdd(&g[u & 0x7FFu], 1u);
  }
}

// ---------- compaction: u > T -> cand ; u == T -> eqbuf ----------
__global__ void k_compact(const float* __restrict__ cls, const unsigned* __restrict__ b1,
                          const unsigned* __restrict__ b2, const unsigned* __restrict__ b3,
                          unsigned* __restrict__ cand, unsigned* __restrict__ candCnt,
                          unsigned* __restrict__ eqbuf, unsigned* __restrict__ eqCnt){
  int img = blockIdx.y;
  unsigned T = (b1[img] << 22) | (b2[img] << 11) | b3[img];
  const float* p = cls + (size_t)img * NN;
  int stride = gridDim.x * blockDim.x;
  for (int i = blockIdx.x * blockDim.x + threadIdx.x; i < NN; i += stride){
    unsigned u = f2u(p[i]);
    if (u > T){
      unsigned pos = atomicAdd(&candCnt[img], 1u);
      if (pos < 2048) cand[img * 2048 + pos] = (unsigned)i;
    } else if (u == T){
      unsigned pos = atomicAdd(&eqCnt[img], 1u);
      if (pos < 8192) eqbuf[img * 8192 + pos] = (unsigned)i;
    }
  }
}

// ---------- resolve exact ties at threshold: need smallest indices ----------
__global__ void k_finalize(unsigned* __restrict__ cand, const unsigned* __restrict__ candCnt,
                           const unsigned* __restrict__ eqbuf, const unsigned* __restrict__ eqCnt,
                           const unsigned* __restrict__ need3){
  __shared__ unsigned a[8192];
  int img = blockIdx.x, tid = threadIdx.x;
  unsigned need = need3[img];
  unsigned ec = eqCnt[img]; if (ec > 8192u) ec = 8192u;
  unsigned base = candCnt[img];
  const unsigned* eq = eqbuf + img * 8192;
  unsigned* c = cand + img * 2048;
  if (need >= ec){
    for (unsigned t = tid; t < ec; t += 256) if (base + t < 2048) c[base + t] = eq[t];
  } else {
    for (int t = tid; t < 8192; t += 256) a[t] = (t < (int)ec) ? eq[t] : 0xFFFFFFFFu;
    __syncthreads();
    for (int kk = 2; kk <= 8192; kk <<= 1){
      for (int j = kk >> 1; j > 0; j >>= 1){
        for (int i = tid; i < 8192; i += 256){
          int ixj = i ^ j;
          if (ixj > i){
            unsigned x = a[i], y = a[ixj];
            bool up = ((i & kk) == 0);
            if (up ? (x > y) : (x < y)){ a[i] = y; a[ixj] = x; }
          }
        }
        __syncthreads();
      }
    }
    for (unsigned t = tid; t < need; t += 256) if (base + t < 2048) c[base + t] = a[t];
  }
}

// ---------- decode + clip + validity + sort key ----------
__global__ void k_decode(const float* __restrict__ cls, const float* __restrict__ reg,
                         const float* __restrict__ anch, const unsigned* __restrict__ cand,
                         float* __restrict__ boxTmp, ull* __restrict__ keys){
  int s = blockIdx.x * blockDim.x + threadIdx.x;
  if (s >= NB * 2048) return;
  int img = s >> 11, slot = s & 2047;
  ull* kp = keys + img * 2048 + slot;
  if (slot >= PRE){ *kp = 0ull; return; }
  unsigned i = cand[img * 2048 + slot];
  if (i >= NN) i = 0;               // safety vs (extremely unlikely) eq-overflow
  size_t gi = (size_t)img * NN + i;
  float4 a = ((const float4*)anch)[gi];
  float4 r = ((const float4*)reg)[gi];
  float sc = cls[gi];
  float aw = a.z - a.x, ah = a.w - a.y;
  float acx = a.x + 0.5f * aw, acy = a.y + 0.5f * ah;
  float pcx = r.x * aw + acx, pcy = r.y * ah + acy;
  float pw = expf(r.z) * aw, ph = expf(r.w) * ah;
  float x1 = pcx - 0.5f * pw, y1 = pcy - 0.5f * ph;
  float x2 = pcx + 0.5f * pw, y2 = pcy + 0.5f * ph;
  x1 = fminf(fmaxf(x1, 0.f), 1333.f); x2 = fminf(fmaxf(x2, 0.f), 1333.f);
  y1 = fminf(fmaxf(y1, 0.f), 800.f);  y2 = fminf(fmaxf(y2, 0.f), 800.f);
  bool valid = ((x2 - x1) >= 0.001f) && ((y2 - y1) >= 0.001f);
  unsigned up = valid ? f2u(sc) : 0u;
  *kp = ((ull)up << 32) | (ull)(0xFFFFFFFFu - i);   // score desc, then index asc
  ((float4*)boxTmp)[img * PRE + slot] = make_float4(x1, y1, x2, y2);
}

// ---------- per-image bitonic sort of 2048 (key desc), gather boxes ----------
__global__ __launch_bounds__(1024) void k_sort(const ull* __restrict__ keys,
                                               const float* __restrict__ boxTmp,
                                               float* __restrict__ sorted,
                                               unsigned* __restrict__ nvalid){
  __shared__ ull k[2048];
  __shared__ unsigned short p[2048];
  __shared__ unsigned nv;
  int img = blockIdx.x, tid = threadIdx.x;
  for (int i = tid; i < 2048; i += 1024){ k[i] = keys[img * 2048 + i]; p[i] = (unsigned short)i; }
  if (tid == 0) nv = 0;
  __syncthreads();
  for (int kk = 2; kk <= 2048; kk <<= 1){
    for (int j = kk >> 1; j > 0; j >>= 1){
      for (int i = tid; i < 2048; i += 1024){
        int ixj = i ^ j;
        if (ixj > i){
          ull ka = k[i], kb = k[ixj];
          bool up = ((i & kk) == 0);
          if (up ? (ka < kb) : (ka > kb)){
            k[i] = kb; k[ixj] = ka;
            unsigned short t2 = p[i]; p[i] = p[ixj]; p[ixj] = t2;
          }
        }
      }
      __syncthreads();
    }
  }
  unsigned c = 0;
  for (int r = tid; r < PRE; r += 1024){
    int slot = p[r];
    ((float4*)sorted)[img * PRE + r] = ((const float4*)boxTmp)[img * PRE + slot];
    if ((unsigned)(k[r] >> 32) != 0u) c++;
  }
  atomicAdd(&nv, c);
  __syncthreads();
  if (tid == 0) nvalid[img] = nv;
}

// ---------- suppression bitmask (j > i, iou > 0.7) + nonzero-row bitmap ----------
__global__ void k_mask(const float* __restrict__ sorted, const unsigned* __restrict__ nvalid,
                       ull* __restrict__ mask, ull* __restrict__ bitmap){
  __shared__ float4 bx[PRE];
  __shared__ unsigned rowflag[8];
  int img = blockIdx.y, tid = threadIdx.x;
  if (tid < 8) rowflag[tid] = 0;
  for (int i = tid; i < PRE; i += 256) bx[i] = ((const float4*)sorted)[img * PRE + i];
  __syncthreads();
  int row = blockIdx.x * 8 + (tid >> 5);
  int word = tid & 31;
  float4 bi = bx[row];
  float ai = (bi.z - bi.x) * (bi.w - bi.y);
  int j0 = word << 6;
  int qlo = row + 1 - j0; if (qlo < 0) qlo = 0;
  int qhi = PRE - j0;     if (qhi > 64) qhi = 64;
  ull m = 0;
  for (int q = qlo; q < qhi; q++){
    float4 bj = bx[j0 + q];
    float xx1 = fmaxf(bi.x, bj.x), yy1 = fmaxf(bi.y, bj.y);
    float xx2 = fminf(bi.z, bj.z), yy2 = fminf(bi.w, bj.w);
    float w = fmaxf(xx2 - xx1, 0.f), h = fmaxf(yy2 - yy1, 0.f);
    float inter = w * h;
    float aj = (bj.z - bj.x) * (bj.w - bj.y);
    float uni = ai + aj - inter;
    if (inter / fmaxf(uni, 1e-8f) > 0.7f) m |= (1ull << q);
  }
  mask[((size_t)(img * PRE + row)) * 32 + word] = m;
  if (m) atomicOr(&rowflag[tid >> 5], 1u);
  __syncthreads();
  if (tid < 8){
    int r = blockIdx.x * 8 + tid;
    if (rowflag[tid] && r < (int)nvalid[img])
      atomicOr(&bitmap[img * 32 + (r >> 6)], 1ull << (r & 63));
  }
}

// ---------- serial NMS scan (only nonzero rows) + rank/scatter output ----------
__global__ __launch_bounds__(64) void k_nms(const ull* __restrict__ mask,
                                            const ull* __restrict__ bitmap,
                                            const unsigned* __restrict__ nvalid,
                                            const float* __restrict__ sorted,
                                            float* __restrict__ out){
  __shared__ unsigned rows[2048];
  __shared__ int mcount;
  __shared__ ull cache[192 * 32];
  __shared__ ull keepArr[32];
  __shared__ unsigned cntArr[32], preArr[32];
  int img = blockIdx.x, lane = threadIdx.x;
  if (lane == 0){
    int m = 0;
    for (int w = 0; w < 32; w++){
      ull bits = bitmap[img * 32 + w];
      while (bits){
        int b = __ffsll(bits) - 1;
        rows[m++] = (unsigned)(w * 64 + b);
        bits &= bits - 1;
      }
    }
    mcount = m;
  }
  __syncthreads();
  int m = mcount;
  ull remv = 0;
  for (int base = 0; base < m; base += 192){
    int cnt = min(192, m - base);
    for (int t = lane; t < cnt * 32; t += 64){
      unsigned rr = rows[base + (t >> 5)];
      cache[t] = mask[((size_t)(img * PRE + rr)) * 32 + (t & 31)];
    }
    __syncthreads();
    for (int q = 0; q < cnt; q++){
      int i = (int)rows[base + q];
      int wi = i >> 6, bi = i & 63;
      int sup = (lane == wi) && ((remv >> bi) & 1ull);
      if (!__any(sup)){
        if (lane < 32) remv |= cache[(q << 5) + lane];
      }
    }
    __syncthreads();
  }
  int nv = (int)nvalid[img];
  if (lane < 32){
    int lo = lane << 6;
    ull vm;
    if (nv <= lo) vm = 0ull;
    else if (nv >= lo + 64) vm = ~0ull;
    else vm = (1ull << (nv - lo)) - 1ull;
    ull kw = (~remv) & vm;
    keepArr[lane] = kw; cntArr[lane] = (unsigned)__popcll(kw);
  }
  __syncthreads();
  if (lane < 32){
    unsigned pre = 0;
    for (int w = 0; w < lane; w++) pre += cntArr[w];
    preArr[lane] = pre;
  }
  __syncthreads();
  for (int i = lane; i < PRE; i += 64){
    int w = i >> 6, b = i & 63;
    ull kw = keepArr[w];
    if ((kw >> b) & 1ull){
      unsigned rank = preArr[w] + (unsigned)__popcll(kw & ((1ull << b) - 1ull));
      if (rank < POST)
        ((float4*)out)[img * POST + rank] = ((const float4*)sorted)[img * PRE + i];
    }
  }
}

extern "C" void kernel_launch(void* const* d_in, const int* in_sizes, int n_in,
                              void* d_out, int out_size, void* d_ws, size_t ws_size,
                              hipStream_t stream){
  const float* cls  = (const float*)d_in[0];
  const float* reg  = (const float*)d_in[1];
  const float* anch = (const float*)d_in[2];
  float* out = (float*)d_out;
  char* ws = (char*)d_ws;

  unsigned* hist1   = (unsigned*)(ws + OFF_HIST1);
  unsigned* hist2   = (unsigned*)(ws + OFF_HIST2);
  unsigned* hist3   = (unsigned*)(ws + OFF_HIST3);
  unsigned* candCnt = (unsigned*)(ws + OFF_CANDCNT);
  unsigned* eqCnt   = (unsigned*)(ws + OFF_EQCNT);
  ull*      bitmap  = (ull*)     (ws + OFF_BITMAP);
  unsigned* b1      = (unsigned*)(ws + OFF_B1);
  unsigned* need1   = (unsigned*)(ws + OFF_NEED1);
  unsigned* b2      = (unsigned*)(ws + OFF_B2);
  unsigned* need2   = (unsigned*)(ws + OFF_NEED2);
  unsigned* b3      = (unsigned*)(ws + OFF_B3);
  unsigned* need3   = (unsigned*)(ws + OFF_NEED3);
  unsigned* cand    = (unsigned*)(ws + OFF_CAND);
  unsigned* eqbuf   = (unsigned*)(ws + OFF_EQBUF);
  float*    boxTmp  = (float*)   (ws + OFF_BOXTMP);
  ull*      keys    = (ull*)     (ws + OFF_KEYS);
  float*    sorted  = (float*)   (ws + OFF_SORTED);
  unsigned* nvalid  = (unsigned*)(ws + OFF_NVALID);
  ull*      mask    = (ull*)     (ws + OFF_MASK);

  hipMemsetAsync(ws, 0, ZERO_BYTES, stream);
  hipMemsetAsync(d_out, 0, (size_t)out_size * sizeof(float), stream);

  k_hist1<<<dim3(32, NB), 256, 0, stream>>>(cls, hist1);
  k_scan <<<NB, 256, 0, stream>>>(hist1, 1024, (const unsigned*)nullptr, 2000u, b1, need1);
  k_hist2<<<dim3(64, NB), 256, 0, stream>>>(cls, b1, hist2);
  k_scan <<<NB, 256, 0, stream>>>(hist2, 2048, need1, 0u, b2, need2);
  k_hist3<<<dim3(64, NB), 256, 0, stream>>>(cls, b1, b2, hist3);
  k_scan <<<NB, 256, 0, stream>>>(hist3, 2048, need2, 0u, b3, need3);
  k_compact<<<dim3(64, NB), 256, 0, stream>>>(cls, b1, b2, b3, cand, candCnt, eqbuf, eqCnt);
  k_finalize<<<NB, 256, 0, stream>>>(cand, candCnt, eqbuf, eqCnt, need3);
  k_decode<<<(NB * 2048) / 256, 256, 0, stream>>>(cls, reg, anch, cand, boxTmp, keys);
  k_sort<<<NB, 1024, 0, stream>>>(keys, boxTmp, sorted, nvalid);
  k_mask<<<dim3(PRE / 8, NB), 256, 0, stream>>>(sorted, nvalid, mask, bitmap);
  k_nms<<<NB, 64, 0, stream>>>(mask, bitmap, nvalid, sorted, out);
}

// Round 2
// 695.591 us; speedup vs baseline: 1.4619x; 1.4619x over previous
//
#include <hip/hip_runtime.h>

#define NB 16
#define NN 300000
#define PRE 2000
#define POST 1000

typedef unsigned long long ull;

// ---------- workspace layout (bytes) ----------
static const size_t OFF_HIST1   = 0;                       // 16*1024*4 = 65536
static const size_t OFF_HIST2   = 65536;                   // 16*2048*4 = 131072
static const size_t OFF_HIST3   = 196608;                  // 131072
static const size_t OFF_CANDCNT = 327680;                  // 64 (pad 256)
static const size_t OFF_EQCNT   = 327936;                  // 64 (pad 256)
static const size_t OFF_BITMAP  = 328192;                  // 16*32*8 = 4096
static const size_t OFF_B1      = 332288;
static const size_t OFF_NEED1   = 332544;
static const size_t OFF_B2      = 332800;
static const size_t OFF_NEED2   = 333056;
static const size_t OFF_B3      = 333312;
static const size_t OFF_NEED3   = 333568;
static const size_t ZERO_BYTES  = 333824;                  // memset region
static const size_t OFF_CAND    = 333824;                  // 16*2048*4 = 131072
static const size_t OFF_EQBUF   = 464896;                  // 16*8192*4 = 524288
static const size_t OFF_BOXTMP  = 989184;                  // 16*2000*16 = 512000
static const size_t OFF_KEYS    = 1501184;                 // 16*2048*8 = 262144
static const size_t OFF_SORTED  = 1763328;                 // 512000
static const size_t OFF_NVALID  = 2275328;                 // 64 (pad 256)
static const size_t OFF_MASK    = 2275584;                 // 16*2000*32*8 = 8192000

__device__ __forceinline__ unsigned f2u(float f){
  unsigned b = __float_as_uint(f);
  return (b & 0x80000000u) ? ~b : (b | 0x80000000u);
}

// ---------- pass 1 histogram: top 10 bits ----------
__global__ void k_hist1(const float* __restrict__ cls, unsigned* __restrict__ hist){
  __shared__ unsigned h[1024];
  int img = blockIdx.y;
  for (int i = threadIdx.x; i < 1024; i += blockDim.x) h[i] = 0;
  __syncthreads();
  const float* p = cls + (size_t)img * NN;
  int stride = gridDim.x * blockDim.x;
  for (int i = blockIdx.x * blockDim.x + threadIdx.x; i < NN; i += stride)
    atomicAdd(&h[f2u(p[i]) >> 22], 1u);
  __syncthreads();
  unsigned* g = hist + img * 1024;
  for (int i = threadIdx.x; i < 1024; i += blockDim.x){
    unsigned v = h[i];
    if (v) atomicAdd(&g[i], v);
  }
}

// ---------- generic descending rank-select over a histogram ----------
__global__ void k_scan(const unsigned* __restrict__ hist, int bins,
                       const unsigned* __restrict__ tgt, unsigned K0,
                       unsigned* __restrict__ outBin, unsigned* __restrict__ outNeed){
  int img = blockIdx.x;
  int t = threadIdx.x;
  const unsigned* hh = hist + img * bins;
  unsigned K = tgt ? tgt[img] : K0;
  int per = bins >> 8;
  unsigned s = 0;
  for (int q = 0; q < per; q++) s += hh[bins - 1 - (t * per + q)];
  __shared__ unsigned arr[256];
  arr[t] = s;
  __syncthreads();
  for (int off = 1; off < 256; off <<= 1){
    unsigned v = (t >= off) ? arr[t - off] : 0u;
    __syncthreads();
    arr[t] += v;
    __syncthreads();
  }
  unsigned incl = arr[t], excl = incl - s;
  if (excl < K && K <= incl){
    unsigned c = excl;
    for (int q = 0; q < per; q++){
      int b = bins - 1 - (t * per + q);
      unsigned cnt = hh[b];
      if (c + cnt >= K){ outBin[img] = (unsigned)b; outNeed[img] = K - c; break; }
      c += cnt;
    }
  }
}

// ---------- pass 2 histogram: bits 21..11 within bin b1 ----------
__global__ void k_hist2(const float* __restrict__ cls, const unsigned* __restrict__ b1,
                        unsigned* __restrict__ hist){
  int img = blockIdx.y;
  unsigned bb1 = b1[img];
  const float* p = cls + (size_t)img * NN;
  unsigned* g = hist + img * 2048;
  int stride = gridDim.x * blockDim.x;
  for (int i = blockIdx.x * blockDim.x + threadIdx.x; i < NN; i += stride){
    unsigned u = f2u(p[i]);
    if ((u >> 22) == bb1) atomicAdd(&g[(u >> 11) & 0x7FFu], 1u);
  }
}

// ---------- pass 3 histogram: bits 10..0 within (b1,b2) ----------
__global__ void k_hist3(const float* __restrict__ cls, const unsigned* __restrict__ b1,
                        const unsigned* __restrict__ b2, unsigned* __restrict__ hist){
  int img = blockIdx.y;
  unsigned pref = (b1[img] << 11) | b2[img];
  const float* p = cls + (size_t)img * NN;
  unsigned* g = hist + img * 2048;
  int stride = gridDim.x * blockDim.x;
  for (int i = blockIdx.x * blockDim.x + threadIdx.x; i < NN; i += stride){
    unsigned u = f2u(p[i]);
    if ((u >> 11) == pref) atomicAdd(&g[u & 0x7FFu], 1u);
  }
}

// ---------- compaction: u > T -> cand ; u == T -> eqbuf ----------
__global__ void k_compact(const float* __restrict__ cls, const unsigned* __restrict__ b1,
                          const unsigned* __restrict__ b2, const unsigned* __restrict__ b3,
                          unsigned* __restrict__ cand, unsigned* __restrict__ candCnt,
                          unsigned* __restrict__ eqbuf, unsigned* __restrict__ eqCnt){
  int img = blockIdx.y;
  unsigned T = (b1[img] << 22) | (b2[img] << 11) | b3[img];
  const float* p = cls + (size_t)img * NN;
  int stride = gridDim.x * blockDim.x;
  for (int i = blockIdx.x * blockDim.x + threadIdx.x; i < NN; i += stride){
    unsigned u = f2u(p[i]);
    if (u > T){
      unsigned pos = atomicAdd(&candCnt[img], 1u);
      if (pos < 2048) cand[img * 2048 + pos] = (unsigned)i;
    } else if (u == T){
      unsigned pos = atomicAdd(&eqCnt[img], 1u);
      if (pos < 8192) eqbuf[img * 8192 + pos] = (unsigned)i;
    }
  }
}

// ---------- resolve exact ties at threshold via rank-selection ----------
// Order within cand[] is irrelevant: k_sort's key = (score, ~index) fixes the
// final order. We only need the SET of the `need` smallest tied indices.
// ec is tiny in practice (exact float duplicates at the threshold value), so
// O(ec^2) comparisons beat any sort; no barrier-heavy latency chain.
__global__ void k_finalize(unsigned* __restrict__ cand, const unsigned* __restrict__ candCnt,
                           const unsigned* __restrict__ eqbuf, const unsigned* __restrict__ eqCnt,
                           const unsigned* __restrict__ need3){
  __shared__ unsigned a[8192];
  int img = blockIdx.x, tid = threadIdx.x;
  unsigned need = need3[img];
  unsigned ec = eqCnt[img]; if (ec > 8192u) ec = 8192u;
  unsigned base = candCnt[img];
  const unsigned* eq = eqbuf + img * 8192;
  unsigned* c = cand + img * 2048;
  if (need >= ec){
    for (unsigned t = tid; t < ec; t += 256) if (base + t < 2048u) c[base + t] = eq[t];
    return;
  }
  for (unsigned t = tid; t < ec; t += 256) a[t] = eq[t];
  __syncthreads();
  for (unsigned t = tid; t < ec; t += 256){
    unsigned v = a[t], r = 0;
    for (unsigned s = 0; s < ec; s++) r += (a[s] < v) ? 1u : 0u;
    if (r < need && base + r < 2048u) c[base + r] = v;
  }
}

// ---------- decode + clip + validity + sort key ----------
__global__ void k_decode(const float* __restrict__ cls, const float* __restrict__ reg,
                         const float* __restrict__ anch, const unsigned* __restrict__ cand,
                         float* __restrict__ boxTmp, ull* __restrict__ keys){
  int s = blockIdx.x * blockDim.x + threadIdx.x;
  if (s >= NB * 2048) return;
  int img = s >> 11, slot = s & 2047;
  ull* kp = keys + img * 2048 + slot;
  if (slot >= PRE){ *kp = 0ull; return; }
  unsigned i = cand[img * 2048 + slot];
  if (i >= NN) i = 0;               // safety vs (extremely unlikely) eq-overflow
  size_t gi = (size_t)img * NN + i;
  float4 a = ((const float4*)anch)[gi];
  float4 r = ((const float4*)reg)[gi];
  float sc = cls[gi];
  float aw = a.z - a.x, ah = a.w - a.y;
  float acx = a.x + 0.5f * aw, acy = a.y + 0.5f * ah;
  float pcx = r.x * aw + acx, pcy = r.y * ah + acy;
  float pw = expf(r.z) * aw, ph = expf(r.w) * ah;
  float x1 = pcx - 0.5f * pw, y1 = pcy - 0.5f * ph;
  float x2 = pcx + 0.5f * pw, y2 = pcy + 0.5f * ph;
  x1 = fminf(fmaxf(x1, 0.f), 1333.f); x2 = fminf(fmaxf(x2, 0.f), 1333.f);
  y1 = fminf(fmaxf(y1, 0.f), 800.f);  y2 = fminf(fmaxf(y2, 0.f), 800.f);
  bool valid = ((x2 - x1) >= 0.001f) && ((y2 - y1) >= 0.001f);
  unsigned up = valid ? f2u(sc) : 0u;
  *kp = ((ull)up << 32) | (ull)(0xFFFFFFFFu - i);   // score desc, then index asc
  ((float4*)boxTmp)[img * PRE + slot] = make_float4(x1, y1, x2, y2);
}

// ---------- per-image bitonic sort of 2048 (key desc), gather boxes ----------
__global__ __launch_bounds__(1024) void k_sort(const ull* __restrict__ keys,
                                               const float* __restrict__ boxTmp,
                                               float* __restrict__ sorted,
                                               unsigned* __restrict__ nvalid){
  __shared__ ull k[2048];
  __shared__ unsigned short p[2048];
  __shared__ unsigned nv;
  int img = blockIdx.x, tid = threadIdx.x;
  for (int i = tid; i < 2048; i += 1024){ k[i] = keys[img * 2048 + i]; p[i] = (unsigned short)i; }
  if (tid == 0) nv = 0;
  __syncthreads();
  for (int kk = 2; kk <= 2048; kk <<= 1){
    for (int j = kk >> 1; j > 0; j >>= 1){
      for (int i = tid; i < 2048; i += 1024){
        int ixj = i ^ j;
        if (ixj > i){
          ull ka = k[i], kb = k[ixj];
          bool up = ((i & kk) == 0);
          if (up ? (ka < kb) : (ka > kb)){
            k[i] = kb; k[ixj] = ka;
            unsigned short t2 = p[i]; p[i] = p[ixj]; p[ixj] = t2;
          }
        }
      }
      __syncthreads();
    }
  }
  unsigned c = 0;
  for (int r = tid; r < PRE; r += 1024){
    int slot = p[r];
    ((float4*)sorted)[img * PRE + r] = ((const float4*)boxTmp)[img * PRE + slot];
    if ((unsigned)(k[r] >> 32) != 0u) c++;
  }
  atomicAdd(&nv, c);
  __syncthreads();
  if (tid == 0) nvalid[img] = nv;
}

// ---------- suppression bitmask (j > i, iou > 0.7) + nonzero-row bitmap ----------
__global__ void k_mask(const float* __restrict__ sorted, const unsigned* __restrict__ nvalid,
                       ull* __restrict__ mask, ull* __restrict__ bitmap){
  __shared__ float4 bx[PRE];
  __shared__ unsigned rowflag[8];
  int img = blockIdx.y, tid = threadIdx.x;
  if (tid < 8) rowflag[tid] = 0;
  for (int i = tid; i < PRE; i += 256) bx[i] = ((const float4*)sorted)[img * PRE + i];
  __syncthreads();
  int row = blockIdx.x * 8 + (tid >> 5);
  int word = tid & 31;
  float4 bi = bx[row];
  float ai = (bi.z - bi.x) * (bi.w - bi.y);
  int j0 = word << 6;
  int qlo = row + 1 - j0; if (qlo < 0) qlo = 0;
  int qhi = PRE - j0;     if (qhi > 64) qhi = 64;
  ull m = 0;
  for (int q = qlo; q < qhi; q++){
    float4 bj = bx[j0 + q];
    float xx1 = fmaxf(bi.x, bj.x), yy1 = fmaxf(bi.y, bj.y);
    float xx2 = fminf(bi.z, bj.z), yy2 = fminf(bi.w, bj.w);
    float w = fmaxf(xx2 - xx1, 0.f), h = fmaxf(yy2 - yy1, 0.f);
    float inter = w * h;
    float aj = (bj.z - bj.x) * (bj.w - bj.y);
    float uni = ai + aj - inter;
    if (inter / fmaxf(uni, 1e-8f) > 0.7f) m |= (1ull << q);
  }
  mask[((size_t)(img * PRE + row)) * 32 + word] = m;
  if (m) atomicOr(&rowflag[tid >> 5], 1u);
  __syncthreads();
  if (tid < 8){
    int r = blockIdx.x * 8 + tid;
    if (rowflag[tid] && r < (int)nvalid[img])
      atomicOr(&bitmap[img * 32 + (r >> 6)], 1ull << (r & 63));
  }
}

// ---------- serial NMS scan (only nonzero rows) + rank/scatter output ----------
__global__ __launch_bounds__(64) void k_nms(const ull* __restrict__ mask,
                                            const ull* __restrict__ bitmap,
                                            const unsigned* __restrict__ nvalid,
                                            const float* __restrict__ sorted,
                                            float* __restrict__ out){
  __shared__ unsigned rows[2048];
  __shared__ int mcount;
  __shared__ ull cache[192 * 32];
  __shared__ ull keepArr[32];
  __shared__ unsigned cntArr[32], preArr[32];
  int img = blockIdx.x, lane = threadIdx.x;
  if (lane == 0){
    int m = 0;
    for (int w = 0; w < 32; w++){
      ull bits = bitmap[img * 32 + w];
      while (bits){
        int b = __ffsll(bits) - 1;
        rows[m++] = (unsigned)(w * 64 + b);
        bits &= bits - 1;
      }
    }
    mcount = m;
  }
  __syncthreads();
  int m = mcount;
  ull remv = 0;
  for (int base = 0; base < m; base += 192){
    int cnt = min(192, m - base);
    for (int t = lane; t < cnt * 32; t += 64){
      unsigned rr = rows[base + (t >> 5)];
      cache[t] = mask[((size_t)(img * PRE + rr)) * 32 + (t & 31)];
    }
    __syncthreads();
    for (int q = 0; q < cnt; q++){
      int i = (int)rows[base + q];
      int wi = i >> 6, bi = i & 63;
      int sup = (lane == wi) && ((remv >> bi) & 1ull);
      if (!__any(sup)){
        if (lane < 32) remv |= cache[(q << 5) + lane];
      }
    }
    __syncthreads();
  }
  int nv = (int)nvalid[img];
  if (lane < 32){
    int lo = lane << 6;
    ull vm;
    if (nv <= lo) vm = 0ull;
    else if (nv >= lo + 64) vm = ~0ull;
    else vm = (1ull << (nv - lo)) - 1ull;
    ull kw = (~remv) & vm;
    keepArr[lane] = kw; cntArr[lane] = (unsigned)__popcll(kw);
  }
  __syncthreads();
  if (lane < 32){
    unsigned pre = 0;
    for (int w = 0; w < lane; w++) pre += cntArr[w];
    preArr[lane] = pre;
  }
  __syncthreads();
  for (int i = lane; i < PRE; i += 64){
    int w = i >> 6, b = i & 63;
    ull kw = keepArr[w];
    if ((kw >> b) & 1ull){
      unsigned rank = preArr[w] + (unsigned)__popcll(kw & ((1ull << b) - 1ull));
      if (rank < POST)
        ((float4*)out)[img * POST + rank] = ((const float4*)sorted)[img * PRE + i];
    }
  }
}

extern "C" void kernel_launch(void* const* d_in, const int* in_sizes, int n_in,
                              void* d_out, int out_size, void* d_ws, size_t ws_size,
                              hipStream_t stream){
  const float* cls  = (const float*)d_in[0];
  const float* reg  = (const float*)d_in[1];
  const float* anch = (const float*)d_in[2];
  float* out = (float*)d_out;
  char* ws = (char*)d_ws;

  unsigned* hist1   = (unsigned*)(ws + OFF_HIST1);
  unsigned* hist2   = (unsigned*)(ws + OFF_HIST2);
  unsigned* hist3   = (unsigned*)(ws + OFF_HIST3);
  unsigned* candCnt = (unsigned*)(ws + OFF_CANDCNT);
  unsigned* eqCnt   = (unsigned*)(ws + OFF_EQCNT);
  ull*      bitmap  = (ull*)     (ws + OFF_BITMAP);
  unsigned* b1      = (unsigned*)(ws + OFF_B1);
  unsigned* need1   = (unsigned*)(ws + OFF_NEED1);
  unsigned* b2      = (unsigned*)(ws + OFF_B2);
  unsigned* need2   = (unsigned*)(ws + OFF_NEED2);
  unsigned* b3      = (unsigned*)(ws + OFF_B3);
  unsigned* need3   = (unsigned*)(ws + OFF_NEED3);
  unsigned* cand    = (unsigned*)(ws + OFF_CAND);
  unsigned* eqbuf   = (unsigned*)(ws + OFF_EQBUF);
  float*    boxTmp  = (float*)   (ws + OFF_BOXTMP);
  ull*      keys    = (ull*)     (ws + OFF_KEYS);
  float*    sorted  = (float*)   (ws + OFF_SORTED);
  unsigned* nvalid  = (unsigned*)(ws + OFF_NVALID);
  ull*      mask    = (ull*)     (ws + OFF_MASK);

  hipMemsetAsync(ws, 0, ZERO_BYTES, stream);
  hipMemsetAsync(d_out, 0, (size_t)out_size * sizeof(float), stream);

  k_hist1<<<dim3(32, NB), 256, 0, stream>>>(cls, hist1);
  k_scan <<<NB, 256, 0, stream>>>(hist1, 1024, (const unsigned*)nullptr, 2000u, b1, need1);
  k_hist2<<<dim3(64, NB), 256, 0, stream>>>(cls, b1, hist2);
  k_scan <<<NB, 256, 0, stream>>>(hist2, 2048, need1, 0u, b2, need2);
  k_hist3<<<dim3(64, NB), 256, 0, stream>>>(cls, b1, b2, hist3);
  k_scan <<<NB, 256, 0, stream>>>(hist3, 2048, need2, 0u, b3, need3);
  k_compact<<<dim3(64, NB), 256, 0, stream>>>(cls, b1, b2, b3, cand, candCnt, eqbuf, eqCnt);
  k_finalize<<<NB, 256, 0, stream>>>(cand, candCnt, eqbuf, eqCnt, need3);
  k_decode<<<(NB * 2048) / 256, 256, 0, stream>>>(cls, reg, anch, cand, boxTmp, keys);
  k_sort<<<NB, 1024, 0, stream>>>(keys, boxTmp, sorted, nvalid);
  k_mask<<<dim3(PRE / 8, NB), 256, 0, stream>>>(sorted, nvalid, mask, bitmap);
  k_nms<<<NB, 64, 0, stream>>>(mask, bitmap, nvalid, sorted, out);
}

// Round 3
// 411.117 us; speedup vs baseline: 2.4734x; 1.6920x over previous
//
#include <hip/hip_runtime.h>

#define NB 16
#define NN 300000
#define PRE 2000
#define POST 1000

typedef unsigned long long ull;

// ---------- workspace layout (bytes) ----------
static const size_t OFF_HIST1   = 0;                       // 16*1024*4 = 65536
static const size_t OFF_HIST2   = 65536;                   // 16*2048*4 = 131072
static const size_t OFF_HIST3   = 196608;                  // 131072
static const size_t OFF_CANDCNT = 327680;                  // 64 (pad 256)
static const size_t OFF_EQCNT   = 327936;                  // 64 (pad 256)
static const size_t OFF_BITMAP  = 328192;                  // 16*32*8 = 4096
static const size_t OFF_B1      = 332288;
static const size_t OFF_NEED1   = 332544;
static const size_t OFF_B2      = 332800;
static const size_t OFF_NEED2   = 333056;
static const size_t OFF_B3      = 333312;
static const size_t OFF_NEED3   = 333568;
static const size_t ZERO_BYTES  = 333824;                  // memset region
static const size_t OFF_CAND    = 333824;                  // 16*2048*4 = 131072
static const size_t OFF_EQBUF   = 464896;                  // 16*8192*4 = 524288
static const size_t OFF_BOXTMP  = 989184;                  // 16*2000*16 = 512000
static const size_t OFF_KEYS    = 1501184;                 // 16*2048*8 = 262144
static const size_t OFF_SORTED  = 1763328;                 // 512000
static const size_t OFF_NVALID  = 2275328;                 // 64 (pad 256)
static const size_t OFF_MASK    = 2275584;                 // 16*2000*32*8 = 8192000

__device__ __forceinline__ unsigned f2u(float f){
  unsigned b = __float_as_uint(f);
  return (b & 0x80000000u) ? ~b : (b | 0x80000000u);
}

// ---------- pass 1 histogram: top 10 bits ----------
__global__ void k_hist1(const float* __restrict__ cls, unsigned* __restrict__ hist){
  __shared__ unsigned h[1024];
  int img = blockIdx.y;
  for (int i = threadIdx.x; i < 1024; i += blockDim.x) h[i] = 0;
  __syncthreads();
  const float* p = cls + (size_t)img * NN;
  int stride = gridDim.x * blockDim.x;
  for (int i = blockIdx.x * blockDim.x + threadIdx.x; i < NN; i += stride)
    atomicAdd(&h[f2u(p[i]) >> 22], 1u);
  __syncthreads();
  unsigned* g = hist + img * 1024;
  for (int i = threadIdx.x; i < 1024; i += blockDim.x){
    unsigned v = h[i];
    if (v) atomicAdd(&g[i], v);
  }
}

// ---------- generic descending rank-select over a histogram ----------
__global__ void k_scan(const unsigned* __restrict__ hist, int bins,
                       const unsigned* __restrict__ tgt, unsigned K0,
                       unsigned* __restrict__ outBin, unsigned* __restrict__ outNeed){
  int img = blockIdx.x;
  int t = threadIdx.x;
  const unsigned* hh = hist + img * bins;
  unsigned K = tgt ? tgt[img] : K0;
  int per = bins >> 8;
  unsigned s = 0;
  for (int q = 0; q < per; q++) s += hh[bins - 1 - (t * per + q)];
  __shared__ unsigned arr[256];
  arr[t] = s;
  __syncthreads();
  for (int off = 1; off < 256; off <<= 1){
    unsigned v = (t >= off) ? arr[t - off] : 0u;
    __syncthreads();
    arr[t] += v;
    __syncthreads();
  }
  unsigned incl = arr[t], excl = incl - s;
  if (excl < K && K <= incl){
    unsigned c = excl;
    for (int q = 0; q < per; q++){
      int b = bins - 1 - (t * per + q);
      unsigned cnt = hh[b];
      if (c + cnt >= K){ outBin[img] = (unsigned)b; outNeed[img] = K - c; break; }
      c += cnt;
    }
  }
}

// ---------- pass 2 histogram: bits 21..11 within bin b1 ----------
__global__ void k_hist2(const float* __restrict__ cls, const unsigned* __restrict__ b1,
                        unsigned* __restrict__ hist){
  int img = blockIdx.y;
  unsigned bb1 = b1[img];
  const float* p = cls + (size_t)img * NN;
  unsigned* g = hist + img * 2048;
  int stride = gridDim.x * blockDim.x;
  for (int i = blockIdx.x * blockDim.x + threadIdx.x; i < NN; i += stride){
    unsigned u = f2u(p[i]);
    if ((u >> 22) == bb1) atomicAdd(&g[(u >> 11) & 0x7FFu], 1u);
  }
}

// ---------- pass 3 histogram: bits 10..0 within (b1,b2) ----------
__global__ void k_hist3(const float* __restrict__ cls, const unsigned* __restrict__ b1,
                        const unsigned* __restrict__ b2, unsigned* __restrict__ hist){
  int img = blockIdx.y;
  unsigned pref = (b1[img] << 11) | b2[img];
  const float* p = cls + (size_t)img * NN;
  unsigned* g = hist + img * 2048;
  int stride = gridDim.x * blockDim.x;
  for (int i = blockIdx.x * blockDim.x + threadIdx.x; i < NN; i += stride){
    unsigned u = f2u(p[i]);
    if ((u >> 11) == pref) atomicAdd(&g[u & 0x7FFu], 1u);
  }
}

// ---------- compaction: u > T -> cand ; u == T -> eqbuf ----------
// Per-block LDS aggregation: one global atomic per block per counter instead
// of one per matching wave. The old version's ~26k same-cacheline device
// atomics serialized at the coherence point (300us @ VALUBusy 0.5%).
// Capacity: #(u>T) <= 1999 total per image, so the 1024-entry LDS buffer
// overflows only in pathological distributions; overflow falls back to
// direct global atomics (set semantics preserved; cand order is irrelevant
// because k_sort orders by the (score,~index) key).
__global__ void k_compact(const float* __restrict__ cls, const unsigned* __restrict__ b1,
                          const unsigned* __restrict__ b2, const unsigned* __restrict__ b3,
                          unsigned* __restrict__ cand, unsigned* __restrict__ candCnt,
                          unsigned* __restrict__ eqbuf, unsigned* __restrict__ eqCnt){
  __shared__ unsigned lc[1024];
  __shared__ unsigned le[256];
  __shared__ unsigned lcn, len_, baseC, baseE;
  int img = blockIdx.y;
  if (threadIdx.x == 0){ lcn = 0; len_ = 0; }
  __syncthreads();
  unsigned T = (b1[img] << 22) | (b2[img] << 11) | b3[img];
  const float* p = cls + (size_t)img * NN;
  int stride = gridDim.x * blockDim.x;
  for (int i = blockIdx.x * blockDim.x + threadIdx.x; i < NN; i += stride){
    unsigned u = f2u(p[i]);
    if (u > T){
      unsigned pos = atomicAdd(&lcn, 1u);
      if (pos < 1024u) lc[pos] = (unsigned)i;
      else { unsigned g = atomicAdd(&candCnt[img], 1u); if (g < 2048u) cand[img * 2048 + g] = (unsigned)i; }
    } else if (u == T){
      unsigned pos = atomicAdd(&len_, 1u);
      if (pos < 256u) le[pos] = (unsigned)i;
      else { unsigned g = atomicAdd(&eqCnt[img], 1u); if (g < 8192u) eqbuf[img * 8192 + g] = (unsigned)i; }
    }
  }
  __syncthreads();
  unsigned nc = lcn < 1024u ? lcn : 1024u;
  unsigned ne = len_ < 256u ? len_ : 256u;
  if (threadIdx.x == 0){
    if (nc) baseC = atomicAdd(&candCnt[img], nc);
    if (ne) baseE = atomicAdd(&eqCnt[img], ne);
  }
  __syncthreads();
  for (unsigned t = threadIdx.x; t < nc; t += blockDim.x){
    unsigned g = baseC + t;
    if (g < 2048u) cand[img * 2048 + g] = lc[t];
  }
  for (unsigned t = threadIdx.x; t < ne; t += blockDim.x){
    unsigned g = baseE + t;
    if (g < 8192u) eqbuf[img * 8192 + g] = le[t];
  }
}

// ---------- resolve exact ties at threshold via rank-selection ----------
// Order within cand[] is irrelevant: k_sort's key = (score, ~index) fixes the
// final order. We only need the SET of the `need` smallest tied indices.
// ec is tiny in practice (exact float duplicates at the threshold value), so
// O(ec^2) comparisons beat any sort; no barrier-heavy latency chain.
__global__ void k_finalize(unsigned* __restrict__ cand, const unsigned* __restrict__ candCnt,
                           const unsigned* __restrict__ eqbuf, const unsigned* __restrict__ eqCnt,
                           const unsigned* __restrict__ need3){
  __shared__ unsigned a[8192];
  int img = blockIdx.x, tid = threadIdx.x;
  unsigned need = need3[img];
  unsigned ec = eqCnt[img]; if (ec > 8192u) ec = 8192u;
  unsigned base = candCnt[img];
  const unsigned* eq = eqbuf + img * 8192;
  unsigned* c = cand + img * 2048;
  if (need >= ec){
    for (unsigned t = tid; t < ec; t += 256) if (base + t < 2048u) c[base + t] = eq[t];
    return;
  }
  for (unsigned t = tid; t < ec; t += 256) a[t] = eq[t];
  __syncthreads();
  for (unsigned t = tid; t < ec; t += 256){
    unsigned v = a[t], r = 0;
    for (unsigned s = 0; s < ec; s++) r += (a[s] < v) ? 1u : 0u;
    if (r < need && base + r < 2048u) c[base + r] = v;
  }
}

// ---------- decode + clip + validity + sort key ----------
__global__ void k_decode(const float* __restrict__ cls, const float* __restrict__ reg,
                         const float* __restrict__ anch, const unsigned* __restrict__ cand,
                         float* __restrict__ boxTmp, ull* __restrict__ keys){
  int s = blockIdx.x * blockDim.x + threadIdx.x;
  if (s >= NB * 2048) return;
  int img = s >> 11, slot = s & 2047;
  ull* kp = keys + img * 2048 + slot;
  if (slot >= PRE){ *kp = 0ull; return; }
  unsigned i = cand[img * 2048 + slot];
  if (i >= NN) i = 0;               // safety vs (extremely unlikely) eq-overflow
  size_t gi = (size_t)img * NN + i;
  float4 a = ((const float4*)anch)[gi];
  float4 r = ((const float4*)reg)[gi];
  float sc = cls[gi];
  float aw = a.z - a.x, ah = a.w - a.y;
  float acx = a.x + 0.5f * aw, acy = a.y + 0.5f * ah;
  float pcx = r.x * aw + acx, pcy = r.y * ah + acy;
  float pw = expf(r.z) * aw, ph = expf(r.w) * ah;
  float x1 = pcx - 0.5f * pw, y1 = pcy - 0.5f * ph;
  float x2 = pcx + 0.5f * pw, y2 = pcy + 0.5f * ph;
  x1 = fminf(fmaxf(x1, 0.f), 1333.f); x2 = fminf(fmaxf(x2, 0.f), 1333.f);
  y1 = fminf(fmaxf(y1, 0.f), 800.f);  y2 = fminf(fmaxf(y2, 0.f), 800.f);
  bool valid = ((x2 - x1) >= 0.001f) && ((y2 - y1) >= 0.001f);
  unsigned up = valid ? f2u(sc) : 0u;
  *kp = ((ull)up << 32) | (ull)(0xFFFFFFFFu - i);   // score desc, then index asc
  ((float4*)boxTmp)[img * PRE + slot] = make_float4(x1, y1, x2, y2);
}

// ---------- per-image bitonic sort of 2048 (key desc), gather boxes ----------
__global__ __launch_bounds__(1024) void k_sort(const ull* __restrict__ keys,
                                               const float* __restrict__ boxTmp,
                                               float* __restrict__ sorted,
                                               unsigned* __restrict__ nvalid){
  __shared__ ull k[2048];
  __shared__ unsigned short p[2048];
  __shared__ unsigned nv;
  int img = blockIdx.x, tid = threadIdx.x;
  for (int i = tid; i < 2048; i += 1024){ k[i] = keys[img * 2048 + i]; p[i] = (unsigned short)i; }
  if (tid == 0) nv = 0;
  __syncthreads();
  for (int kk = 2; kk <= 2048; kk <<= 1){
    for (int j = kk >> 1; j > 0; j >>= 1){
      for (int i = tid; i < 2048; i += 1024){
        int ixj = i ^ j;
        if (ixj > i){
          ull ka = k[i], kb = k[ixj];
          bool up = ((i & kk) == 0);
          if (up ? (ka < kb) : (ka > kb)){
            k[i] = kb; k[ixj] = ka;
            unsigned short t2 = p[i]; p[i] = p[ixj]; p[ixj] = t2;
          }
        }
      }
      __syncthreads();
    }
  }
  unsigned c = 0;
  for (int r = tid; r < PRE; r += 1024){
    int slot = p[r];
    ((float4*)sorted)[img * PRE + r] = ((const float4*)boxTmp)[img * PRE + slot];
    if ((unsigned)(k[r] >> 32) != 0u) c++;
  }
  atomicAdd(&nv, c);
  __syncthreads();
  if (tid == 0) nvalid[img] = nv;
}

// ---------- suppression bitmask (j > i, iou > 0.7) + nonzero-row bitmap ----------
__global__ void k_mask(const float* __restrict__ sorted, const unsigned* __restrict__ nvalid,
                       ull* __restrict__ mask, ull* __restrict__ bitmap){
  __shared__ float4 bx[PRE];
  __shared__ unsigned rowflag[8];
  int img = blockIdx.y, tid = threadIdx.x;
  if (tid < 8) rowflag[tid] = 0;
  for (int i = tid; i < PRE; i += 256) bx[i] = ((const float4*)sorted)[img * PRE + i];
  __syncthreads();
  int row = blockIdx.x * 8 + (tid >> 5);
  int word = tid & 31;
  float4 bi = bx[row];
  float ai = (bi.z - bi.x) * (bi.w - bi.y);
  int j0 = word << 6;
  int qlo = row + 1 - j0; if (qlo < 0) qlo = 0;
  int qhi = PRE - j0;     if (qhi > 64) qhi = 64;
  ull m = 0;
  for (int q = qlo; q < qhi; q++){
    float4 bj = bx[j0 + q];
    float xx1 = fmaxf(bi.x, bj.x), yy1 = fmaxf(bi.y, bj.y);
    float xx2 = fminf(bi.z, bj.z), yy2 = fminf(bi.w, bj.w);
    float w = fmaxf(xx2 - xx1, 0.f), h = fmaxf(yy2 - yy1, 0.f);
    float inter = w * h;
    float aj = (bj.z - bj.x) * (bj.w - bj.y);
    float uni = ai + aj - inter;
    if (inter / fmaxf(uni, 1e-8f) > 0.7f) m |= (1ull << q);
  }
  mask[((size_t)(img * PRE + row)) * 32 + word] = m;
  if (m) atomicOr(&rowflag[tid >> 5], 1u);
  __syncthreads();
  if (tid < 8){
    int r = blockIdx.x * 8 + tid;
    if (rowflag[tid] && r < (int)nvalid[img])
      atomicOr(&bitmap[img * 32 + (r >> 6)], 1ull << (r & 63));
  }
}

// ---------- serial NMS scan (only nonzero rows) + rank/scatter output ----------
__global__ __launch_bounds__(64) void k_nms(const ull* __restrict__ mask,
                                            const ull* __restrict__ bitmap,
                                            const unsigned* __restrict__ nvalid,
                                            const float* __restrict__ sorted,
                                            float* __restrict__ out){
  __shared__ unsigned rows[2048];
  __shared__ int mcount;
  __shared__ ull cache[192 * 32];
  __shared__ ull keepArr[32];
  __shared__ unsigned cntArr[32], preArr[32];
  int img = blockIdx.x, lane = threadIdx.x;
  if (lane == 0){
    int m = 0;
    for (int w = 0; w < 32; w++){
      ull bits = bitmap[img * 32 + w];
      while (bits){
        int b = __ffsll(bits) - 1;
        rows[m++] = (unsigned)(w * 64 + b);
        bits &= bits - 1;
      }
    }
    mcount = m;
  }
  __syncthreads();
  int m = mcount;
  ull remv = 0;
  for (int base = 0; base < m; base += 192){
    int cnt = min(192, m - base);
    for (int t = lane; t < cnt * 32; t += 64){
      unsigned rr = rows[base + (t >> 5)];
      cache[t] = mask[((size_t)(img * PRE + rr)) * 32 + (t & 31)];
    }
    __syncthreads();
    for (int q = 0; q < cnt; q++){
      int i = (int)rows[base + q];
      int wi = i >> 6, bi = i & 63;
      int sup = (lane == wi) && ((remv >> bi) & 1ull);
      if (!__any(sup)){
        if (lane < 32) remv |= cache[(q << 5) + lane];
      }
    }
    __syncthreads();
  }
  int nv = (int)nvalid[img];
  if (lane < 32){
    int lo = lane << 6;
    ull vm;
    if (nv <= lo) vm = 0ull;
    else if (nv >= lo + 64) vm = ~0ull;
    else vm = (1ull << (nv - lo)) - 1ull;
    ull kw = (~remv) & vm;
    keepArr[lane] = kw; cntArr[lane] = (unsigned)__popcll(kw);
  }
  __syncthreads();
  if (lane < 32){
    unsigned pre = 0;
    for (int w = 0; w < lane; w++) pre += cntArr[w];
    preArr[lane] = pre;
  }
  __syncthreads();
  for (int i = lane; i < PRE; i += 64){
    int w = i >> 6, b = i & 63;
    ull kw = keepArr[w];
    if ((kw >> b) & 1ull){
      unsigned rank = preArr[w] + (unsigned)__popcll(kw & ((1ull << b) - 1ull));
      if (rank < POST)
        ((float4*)out)[img * POST + rank] = ((const float4*)sorted)[img * PRE + i];
    }
  }
}

extern "C" void kernel_launch(void* const* d_in, const int* in_sizes, int n_in,
                              void* d_out, int out_size, void* d_ws, size_t ws_size,
                              hipStream_t stream){
  const float* cls  = (const float*)d_in[0];
  const float* reg  = (const float*)d_in[1];
  const float* anch = (const float*)d_in[2];
  float* out = (float*)d_out;
  char* ws = (char*)d_ws;

  unsigned* hist1   = (unsigned*)(ws + OFF_HIST1);
  unsigned* hist2   = (unsigned*)(ws + OFF_HIST2);
  unsigned* hist3   = (unsigned*)(ws + OFF_HIST3);
  unsigned* candCnt = (unsigned*)(ws + OFF_CANDCNT);
  unsigned* eqCnt   = (unsigned*)(ws + OFF_EQCNT);
  ull*      bitmap  = (ull*)     (ws + OFF_BITMAP);
  unsigned* b1      = (unsigned*)(ws + OFF_B1);
  unsigned* need1   = (unsigned*)(ws + OFF_NEED1);
  unsigned* b2      = (unsigned*)(ws + OFF_B2);
  unsigned* need2   = (unsigned*)(ws + OFF_NEED2);
  unsigned* b3      = (unsigned*)(ws + OFF_B3);
  unsigned* need3   = (unsigned*)(ws + OFF_NEED3);
  unsigned* cand    = (unsigned*)(ws + OFF_CAND);
  unsigned* eqbuf   = (unsigned*)(ws + OFF_EQBUF);
  float*    boxTmp  = (float*)   (ws + OFF_BOXTMP);
  ull*      keys    = (ull*)     (ws + OFF_KEYS);
  float*    sorted  = (float*)   (ws + OFF_SORTED);
  unsigned* nvalid  = (unsigned*)(ws + OFF_NVALID);
  ull*      mask    = (ull*)     (ws + OFF_MASK);

  hipMemsetAsync(ws, 0, ZERO_BYTES, stream);
  hipMemsetAsync(d_out, 0, (size_t)out_size * sizeof(float), stream);

  k_hist1<<<dim3(32, NB), 256, 0, stream>>>(cls, hist1);
  k_scan <<<NB, 256, 0, stream>>>(hist1, 1024, (const unsigned*)nullptr, 2000u, b1, need1);
  k_hist2<<<dim3(64, NB), 256, 0, stream>>>(cls, b1, hist2);
  k_scan <<<NB, 256, 0, stream>>>(hist2, 2048, need1, 0u, b2, need2);
  k_hist3<<<dim3(64, NB), 256, 0, stream>>>(cls, b1, b2, hist3);
  k_scan <<<NB, 256, 0, stream>>>(hist3, 2048, need2, 0u, b3, need3);
  k_compact<<<dim3(64, NB), 256, 0, stream>>>(cls, b1, b2, b3, cand, candCnt, eqbuf, eqCnt);
  k_finalize<<<NB, 256, 0, stream>>>(cand, candCnt, eqbuf, eqCnt, need3);
  k_decode<<<(NB * 2048) / 256, 256, 0, stream>>>(cls, reg, anch, cand, boxTmp, keys);
  k_sort<<<NB, 1024, 0, stream>>>(keys, boxTmp, sorted, nvalid);
  k_mask<<<dim3(PRE / 8, NB), 256, 0, stream>>>(sorted, nvalid, mask, bitmap);
  k_nms<<<NB, 64, 0, stream>>>(mask, bitmap, nvalid, sorted, out);
}

// Round 4
// 352.080 us; speedup vs baseline: 2.8881x; 1.1677x over previous
//
#include <hip/hip_runtime.h>

#define NB 16
#define NN 300000
#define PRE 2000
#define POST 1000

typedef unsigned long long ull;

// ---------- workspace layout (bytes) ----------
static const size_t OFF_HIST1   = 0;                       // 16*1024*4 = 65536
static const size_t OFF_HIST2   = 65536;                   // 16*2048*4 = 131072
static const size_t OFF_HIST3   = 196608;                  // 131072
static const size_t OFF_CANDCNT = 327680;                  // 64 (pad 256)
static const size_t OFF_EQCNT   = 327936;                  // 64 (pad 256)
static const size_t OFF_BITMAP  = 328192;                  // 16*32*8 = 4096
static const size_t OFF_B1      = 332288;
static const size_t OFF_NEED1   = 332544;
static const size_t OFF_B2      = 332800;
static const size_t OFF_NEED2   = 333056;
static const size_t OFF_B3      = 333312;
static const size_t OFF_NEED3   = 333568;
static const size_t ZERO_BYTES  = 333824;                  // memset region
static const size_t OFF_CAND    = 333824;                  // 16*2048*4 = 131072
static const size_t OFF_EQBUF   = 464896;                  // 16*8192*4 = 524288
static const size_t OFF_SORTED  = 989184;                  // 16*2000*16 = 512000
static const size_t OFF_NVALID  = 1501184;                 // 64 (pad 256)
static const size_t OFF_MASK    = 1501440;                 // 16*2000*32*8 = 8192000

__device__ __forceinline__ unsigned f2u(float f){
  unsigned b = __float_as_uint(f);
  return (b & 0x80000000u) ? ~b : (b | 0x80000000u);
}

// ---------- pass 1 histogram: top 10 bits (8 replicated LDS copies) ----------
// Normal-distributed scores concentrate in few (sign,exp,m1) bins -> heavy
// same-address LDS atomic serialization with a single copy. 8 replicas with
// stride 1025 (bank-decorrelated) cut the serialization ~8x.
#define H1REP 8
#define H1STRIDE 1025
__global__ void k_hist1(const float* __restrict__ cls, unsigned* __restrict__ hist){
  __shared__ unsigned h[H1REP * H1STRIDE];
  int img = blockIdx.y;
  for (int i = threadIdx.x; i < H1REP * H1STRIDE; i += blockDim.x) h[i] = 0;
  __syncthreads();
  const float* p = cls + (size_t)img * NN;
  int stride = gridDim.x * blockDim.x;
  unsigned rep = (threadIdx.x & (H1REP - 1)) * H1STRIDE;
  for (int i = blockIdx.x * blockDim.x + threadIdx.x; i < NN; i += stride)
    atomicAdd(&h[rep + (f2u(p[i]) >> 22)], 1u);
  __syncthreads();
  unsigned* g = hist + img * 1024;
  for (int i = threadIdx.x; i < 1024; i += blockDim.x){
    unsigned v = 0;
    for (int r = 0; r < H1REP; r++) v += h[r * H1STRIDE + i];
    if (v) atomicAdd(&g[i], v);
  }
}

// ---------- generic descending rank-select over a histogram ----------
__global__ void k_scan(const unsigned* __restrict__ hist, int bins,
                       const unsigned* __restrict__ tgt, unsigned K0,
                       unsigned* __restrict__ outBin, unsigned* __restrict__ outNeed){
  int img = blockIdx.x;
  int t = threadIdx.x;
  const unsigned* hh = hist + img * bins;
  unsigned K = tgt ? tgt[img] : K0;
  int per = bins >> 8;
  unsigned s = 0;
  for (int q = 0; q < per; q++) s += hh[bins - 1 - (t * per + q)];
  __shared__ unsigned arr[256];
  arr[t] = s;
  __syncthreads();
  for (int off = 1; off < 256; off <<= 1){
    unsigned v = (t >= off) ? arr[t - off] : 0u;
    __syncthreads();
    arr[t] += v;
    __syncthreads();
  }
  unsigned incl = arr[t], excl = incl - s;
  if (excl < K && K <= incl){
    unsigned c = excl;
    for (int q = 0; q < per; q++){
      int b = bins - 1 - (t * per + q);
      unsigned cnt = hh[b];
      if (c + cnt >= K){ outBin[img] = (unsigned)b; outNeed[img] = K - c; break; }
      c += cnt;
    }
  }
}

// ---------- pass 2 histogram: bits 21..11 within bin b1 ----------
__global__ void k_hist2(const float* __restrict__ cls, const unsigned* __restrict__ b1,
                        unsigned* __restrict__ hist){
  int img = blockIdx.y;
  unsigned bb1 = b1[img];
  const float* p = cls + (size_t)img * NN;
  unsigned* g = hist + img * 2048;
  int stride = gridDim.x * blockDim.x;
  for (int i = blockIdx.x * blockDim.x + threadIdx.x; i < NN; i += stride){
    unsigned u = f2u(p[i]);
    if ((u >> 22) == bb1) atomicAdd(&g[(u >> 11) & 0x7FFu], 1u);
  }
}

// ---------- pass 3 histogram: bits 10..0 within (b1,b2) ----------
__global__ void k_hist3(const float* __restrict__ cls, const unsigned* __restrict__ b1,
                        const unsigned* __restrict__ b2, unsigned* __restrict__ hist){
  int img = blockIdx.y;
  unsigned pref = (b1[img] << 11) | b2[img];
  const float* p = cls + (size_t)img * NN;
  unsigned* g = hist + img * 2048;
  int stride = gridDim.x * blockDim.x;
  for (int i = blockIdx.x * blockDim.x + threadIdx.x; i < NN; i += stride){
    unsigned u = f2u(p[i]);
    if ((u >> 11) == pref) atomicAdd(&g[u & 0x7FFu], 1u);
  }
}

// ---------- compaction: u > T -> cand ; u == T -> eqbuf (LDS-aggregated) ----------
__global__ void k_compact(const float* __restrict__ cls, const unsigned* __restrict__ b1,
                          const unsigned* __restrict__ b2, const unsigned* __restrict__ b3,
                          unsigned* __restrict__ cand, unsigned* __restrict__ candCnt,
                          unsigned* __restrict__ eqbuf, unsigned* __restrict__ eqCnt){
  __shared__ unsigned lc[1024];
  __shared__ unsigned le[256];
  __shared__ unsigned lcn, len_, baseC, baseE;
  int img = blockIdx.y;
  if (threadIdx.x == 0){ lcn = 0; len_ = 0; }
  __syncthreads();
  unsigned T = (b1[img] << 22) | (b2[img] << 11) | b3[img];
  const float* p = cls + (size_t)img * NN;
  int stride = gridDim.x * blockDim.x;
  for (int i = blockIdx.x * blockDim.x + threadIdx.x; i < NN; i += stride){
    unsigned u = f2u(p[i]);
    if (u > T){
      unsigned pos = atomicAdd(&lcn, 1u);
      if (pos < 1024u) lc[pos] = (unsigned)i;
      else { unsigned g = atomicAdd(&candCnt[img], 1u); if (g < 2048u) cand[img * 2048 + g] = (unsigned)i; }
    } else if (u == T){
      unsigned pos = atomicAdd(&len_, 1u);
      if (pos < 256u) le[pos] = (unsigned)i;
      else { unsigned g = atomicAdd(&eqCnt[img], 1u); if (g < 8192u) eqbuf[img * 8192 + g] = (unsigned)i; }
    }
  }
  __syncthreads();
  unsigned nc = lcn < 1024u ? lcn : 1024u;
  unsigned ne = len_ < 256u ? len_ : 256u;
  if (threadIdx.x == 0){
    if (nc) baseC = atomicAdd(&candCnt[img], nc);
    if (ne) baseE = atomicAdd(&eqCnt[img], ne);
  }
  __syncthreads();
  for (unsigned t = threadIdx.x; t < nc; t += blockDim.x){
    unsigned g = baseC + t;
    if (g < 2048u) cand[img * 2048 + g] = lc[t];
  }
  for (unsigned t = threadIdx.x; t < ne; t += blockDim.x){
    unsigned g = baseE + t;
    if (g < 8192u) eqbuf[img * 8192 + g] = le[t];
  }
}

// ---------- fused: tie-resolve + decode + bitonic sort (one block per image) ----------
// Tie order is irrelevant (key bakes in (score desc, index asc)); we only need
// the SET of the `need` smallest tied indices (O(ec^2), ec tiny).
__global__ __launch_bounds__(1024) void k_sortd(
    const float* __restrict__ cls, const float* __restrict__ reg,
    const float* __restrict__ anch,
    const unsigned* __restrict__ cand, const unsigned* __restrict__ candCnt,
    const unsigned* __restrict__ eqbuf, const unsigned* __restrict__ eqCnt,
    const unsigned* __restrict__ need3,
    float* __restrict__ sorted, unsigned* __restrict__ nvalid){
  __shared__ ull k[2048];
  __shared__ unsigned short p[2048];
  __shared__ unsigned cidx[2048];
  __shared__ float4 bxs[2048];
  __shared__ unsigned nv;
  int img = blockIdx.x, tid = threadIdx.x;
  unsigned need = need3[img];
  unsigned ec = eqCnt[img]; if (ec > 8192u) ec = 8192u;
  unsigned base = candCnt[img]; if (base > 2048u) base = 2048u;
  const unsigned* eq = eqbuf + img * 8192;
  for (int t = tid; t < 2048; t += 1024)
    cidx[t] = (t < (int)base) ? cand[img * 2048 + t] : 0xFFFFFFFFu;
  if (tid == 0) nv = 0;
  __syncthreads();
  if (need >= ec){
    for (unsigned t = tid; t < ec; t += 1024){
      unsigned g = base + t; if (g < 2048u) cidx[g] = eq[t];
    }
  } else {
    for (unsigned t = tid; t < ec; t += 1024){
      unsigned v = eq[t], r = 0;
      for (unsigned s = 0; s < ec; s++) r += (eq[s] < v) ? 1u : 0u;
      if (r < need && base + r < 2048u) cidx[base + r] = v;
    }
  }
  __syncthreads();
  // decode + keys
  for (int t = tid; t < 2048; t += 1024){
    unsigned i = cidx[t];
    ull key = 0ull;
    float4 box = make_float4(0.f, 0.f, 0.f, 0.f);
    if (t < PRE && i < NN){
      size_t gi = (size_t)img * NN + i;
      float4 a = ((const float4*)anch)[gi];
      float4 r4 = ((const float4*)reg)[gi];
      float sc = cls[gi];
      float aw = a.z - a.x, ah = a.w - a.y;
      float acx = a.x + 0.5f * aw, acy = a.y + 0.5f * ah;
      float pcx = r4.x * aw + acx, pcy = r4.y * ah + acy;
      float pw = expf(r4.z) * aw, ph = expf(r4.w) * ah;
      float x1 = pcx - 0.5f * pw, y1 = pcy - 0.5f * ph;
      float x2 = pcx + 0.5f * pw, y2 = pcy + 0.5f * ph;
      x1 = fminf(fmaxf(x1, 0.f), 1333.f); x2 = fminf(fmaxf(x2, 0.f), 1333.f);
      y1 = fminf(fmaxf(y1, 0.f), 800.f);  y2 = fminf(fmaxf(y2, 0.f), 800.f);
      bool valid = ((x2 - x1) >= 0.001f) && ((y2 - y1) >= 0.001f);
      unsigned up = valid ? f2u(sc) : 0u;
      key = ((ull)up << 32) | (ull)(0xFFFFFFFFu - i);   // score desc, index asc
      box = make_float4(x1, y1, x2, y2);
    }
    k[t] = key; bxs[t] = box; p[t] = (unsigned short)t;
  }
  __syncthreads();
  for (int kk = 2; kk <= 2048; kk <<= 1){
    for (int j = kk >> 1; j > 0; j >>= 1){
      for (int i = tid; i < 2048; i += 1024){
        int ixj = i ^ j;
        if (ixj > i){
          ull ka = k[i], kb = k[ixj];
          bool up = ((i & kk) == 0);
          if (up ? (ka < kb) : (ka > kb)){
            k[i] = kb; k[ixj] = ka;
            unsigned short t2 = p[i]; p[i] = p[ixj]; p[ixj] = t2;
          }
        }
      }
      __syncthreads();
    }
  }
  unsigned c = 0;
  for (int r = tid; r < PRE; r += 1024){
    ((float4*)sorted)[img * PRE + r] = bxs[p[r]];
    if ((unsigned)(k[r] >> 32) != 0u) c++;
  }
  atomicAdd(&nv, c);
  __syncthreads();
  if (tid == 0) nvalid[img] = nv;
}

// ---------- suppression bitmask, PERMUTED layout: word w bit q <-> j = 32q+w ----------
// Lane w reads bx[32q+w]: consecutive lanes -> consecutive float4 = phase-
// parallel conflict-free ds_read_b128 (old layout: all lanes on 4 banks).
__global__ __launch_bounds__(512) void k_mask(const float* __restrict__ sorted,
                                              const unsigned* __restrict__ nvalid,
                                              ull* __restrict__ mask, ull* __restrict__ bitmap){
  __shared__ float4 bx[PRE];
  __shared__ float  ar[PRE];
  __shared__ unsigned rowflag[16];
  int img = blockIdx.y, tid = threadIdx.x;
  if (tid < 16) rowflag[tid] = 0;
  for (int i = tid; i < PRE; i += 512){
    float4 b = ((const float4*)sorted)[img * PRE + i];
    bx[i] = b;
    ar[i] = (b.z - b.x) * (b.w - b.y);
  }
  __syncthreads();
  int row = blockIdx.x * 16 + (tid >> 5);
  int w = tid & 31;
  float4 bi = bx[row];
  float ai = ar[row];
  int qlo = (row >= w) ? (((row - w) >> 5) + 1) : 0;
  int qhi = ((PRE - 1 - w) >> 5) + 1;
  ull m = 0;
  for (int q = qlo; q < qhi; q++){
    int j = (q << 5) + w;
    float4 bj = bx[j];
    float xx1 = fmaxf(bi.x, bj.x), yy1 = fmaxf(bi.y, bj.y);
    float xx2 = fminf(bi.z, bj.z), yy2 = fminf(bi.w, bj.w);
    float ww = fmaxf(xx2 - xx1, 0.f), hh = fmaxf(yy2 - yy1, 0.f);
    float inter = ww * hh;
    float uni = ai + ar[j] - inter;
    if (inter / fmaxf(uni, 1e-8f) > 0.7f) m |= (1ull << q);   // keep exact div (bit-match)
  }
  mask[((size_t)(img * PRE + row)) * 32 + w] = m;
  if (m) atomicOr(&rowflag[tid >> 5], 1u);
  __syncthreads();
  if (tid < 16){
    int r = blockIdx.x * 16 + tid;
    if (rowflag[tid] && r < (int)nvalid[img])
      atomicOr(&bitmap[img * 32 + (r >> 6)], 1ull << (r & 63));
  }
}

// ---------- serial NMS scan (nonzero rows only, permuted masks) + rank/scatter ----------
__global__ __launch_bounds__(256) void k_nms(const ull* __restrict__ mask,
                                             const ull* __restrict__ bitmap,
                                             const unsigned* __restrict__ nvalid,
                                             const float* __restrict__ sorted,
                                             float* __restrict__ out){
  __shared__ unsigned rows[2048];
  __shared__ int mcount;
  __shared__ ull cache[192 * 32];
  __shared__ ull keepP[32];     // permuted keep: word w bit q -> j = 32q+w
  __shared__ ull keepLin[32];   // linear keep:   word w bit b -> i = 64w+b
  __shared__ unsigned cntArr[32], preArr[32];
  int img = blockIdx.x, tid = threadIdx.x;
  int lane = tid & 63, wave = tid >> 6;
  if (tid == 0){
    int m = 0;
    for (int w0 = 0; w0 < 32; w0++){
      ull bits = bitmap[img * 32 + w0];
      while (bits){
        int b = __ffsll(bits) - 1;
        rows[m++] = (unsigned)(w0 * 64 + b);   // ascending i order
        bits &= bits - 1;
      }
    }
    mcount = m;
  }
  __syncthreads();
  int m = mcount;
  ull remv = 0;
  for (int base = 0; base < m; base += 192){
    int cnt = min(192, m - base);
    for (int t = tid; t < cnt * 32; t += 256){
      unsigned rr = rows[base + (t >> 5)];
      cache[t] = mask[((size_t)(img * PRE + rr)) * 32 + (t & 31)];
    }
    __syncthreads();
    if (wave == 0){
      for (int q = 0; q < cnt; q++){
        int i = (int)rows[base + q];
        int wi = i & 31, bi = i >> 5;       // permuted coords of i
        int sup = (lane == wi) && ((remv >> bi) & 1ull);
        if (!__any(sup)){
          if (lane < 32) remv |= cache[(q << 5) + lane];
        }
      }
    }
    __syncthreads();
  }
  int nv = (int)nvalid[img];
  if (wave == 0 && lane < 32){
    int cnt2 = (nv > lane) ? (((nv - 1 - lane) >> 5) + 1) : 0;   // #valid q for this word
    ull vm = (cnt2 >= 64) ? ~0ull : ((1ull << cnt2) - 1ull);
    keepP[lane] = (~remv) & vm;
  }
  __syncthreads();
  if (tid < 32){   // permuted -> linear: bit k of lin word wp is i = 64*wp + k
    ull lin = 0;
    for (int kk = 0; kk < 64; kk++)
      lin |= ((keepP[kk & 31] >> (2 * tid + (kk >> 5))) & 1ull) << kk;
    keepLin[tid] = lin;
    cntArr[tid] = (unsigned)__popcll(lin);
  }
  __syncthreads();
  if (tid < 32){
    unsigned pre = 0;
    for (int w0 = 0; w0 < tid; w0++) pre += cntArr[w0];
    preArr[tid] = pre;
  }
  __syncthreads();
  for (int i = tid; i < PRE; i += 256){
    int w0 = i >> 6, b = i & 63;
    ull kw = keepLin[w0];
    if ((kw >> b) & 1ull){
      unsigned rank = preArr[w0] + (unsigned)__popcll(kw & ((1ull << b) - 1ull));
      if (rank < POST)
        ((float4*)out)[img * POST + rank] = ((const float4*)sorted)[img * PRE + i];
    }
  }
}

extern "C" void kernel_launch(void* const* d_in, const int* in_sizes, int n_in,
                              void* d_out, int out_size, void* d_ws, size_t ws_size,
                              hipStream_t stream){
  const float* cls  = (const float*)d_in[0];
  const float* reg  = (const float*)d_in[1];
  const float* anch = (const float*)d_in[2];
  float* out = (float*)d_out;
  char* ws = (char*)d_ws;

  unsigned* hist1   = (unsigned*)(ws + OFF_HIST1);
  unsigned* hist2   = (unsigned*)(ws + OFF_HIST2);
  unsigned* hist3   = (unsigned*)(ws + OFF_HIST3);
  unsigned* candCnt = (unsigned*)(ws + OFF_CANDCNT);
  unsigned* eqCnt   = (unsigned*)(ws + OFF_EQCNT);
  ull*      bitmap  = (ull*)     (ws + OFF_BITMAP);
  unsigned* b1      = (unsigned*)(ws + OFF_B1);
  unsigned* need1   = (unsigned*)(ws + OFF_NEED1);
  unsigned* b2      = (unsigned*)(ws + OFF_B2);
  unsigned* need2   = (unsigned*)(ws + OFF_NEED2);
  unsigned* b3      = (unsigned*)(ws + OFF_B3);
  unsigned* need3   = (unsigned*)(ws + OFF_NEED3);
  unsigned* cand    = (unsigned*)(ws + OFF_CAND);
  unsigned* eqbuf   = (unsigned*)(ws + OFF_EQBUF);
  float*    sorted  = (float*)   (ws + OFF_SORTED);
  unsigned* nvalid  = (unsigned*)(ws + OFF_NVALID);
  ull*      mask    = (ull*)     (ws + OFF_MASK);

  hipMemsetAsync(ws, 0, ZERO_BYTES, stream);
  hipMemsetAsync(d_out, 0, (size_t)out_size * sizeof(float), stream);

  k_hist1<<<dim3(64, NB), 256, 0, stream>>>(cls, hist1);
  k_scan <<<NB, 256, 0, stream>>>(hist1, 1024, (const unsigned*)nullptr, 2000u, b1, need1);
  k_hist2<<<dim3(64, NB), 256, 0, stream>>>(cls, b1, hist2);
  k_scan <<<NB, 256, 0, stream>>>(hist2, 2048, need1, 0u, b2, need2);
  k_hist3<<<dim3(64, NB), 256, 0, stream>>>(cls, b1, b2, hist3);
  k_scan <<<NB, 256, 0, stream>>>(hist3, 2048, need2, 0u, b3, need3);
  k_compact<<<dim3(64, NB), 256, 0, stream>>>(cls, b1, b2, b3, cand, candCnt, eqbuf, eqCnt);
  k_sortd<<<NB, 1024, 0, stream>>>(cls, reg, anch, cand, candCnt, eqbuf, eqCnt, need3,
                                   sorted, nvalid);
  k_mask<<<dim3(PRE / 16, NB), 512, 0, stream>>>(sorted, nvalid, mask, bitmap);
  k_nms<<<NB, 256, 0, stream>>>(mask, bitmap, nvalid, sorted, out);
}

// Round 5
// 336.018 us; speedup vs baseline: 3.0262x; 1.0478x over previous
//
#include <hip/hip_runtime.h>

#define NB 16
#define NN 300000
#define PRE 2000
#define POST 1000

typedef unsigned long long ull;

// ---------- workspace layout (bytes) ----------
static const size_t OFF_HIST1   = 0;                       // 16*1024*4 = 65536
static const size_t OFF_HIST2   = 65536;                   // 16*2048*4 = 131072
static const size_t OFF_HIST3   = 196608;                  // 131072
static const size_t OFF_CANDCNT = 327680;                  // 64 (pad 256)
static const size_t OFF_EQCNT   = 327936;                  // 64 (pad 256)
static const size_t OFF_BITMAP  = 328192;                  // 16*32*8 = 4096
static const size_t OFF_B1      = 332288;
static const size_t OFF_NEED1   = 332544;
static const size_t OFF_B2      = 332800;
static const size_t OFF_NEED2   = 333056;
static const size_t OFF_B3      = 333312;
static const size_t OFF_NEED3   = 333568;
static const size_t OFF_NVALID  = 333824;                  // 64 (pad 256) — atomically accumulated, must be zeroed
static const size_t ZERO_BYTES  = 334080;                  // memset region
static const size_t OFF_CAND    = 334080;                  // 16*2048*4 = 131072
static const size_t OFF_EQBUF   = 465152;                  // 16*8192*4 = 524288
static const size_t OFF_KEYS    = 989440;                  // 16*2048*8 = 262144
static const size_t OFF_BOXTMP  = 1251584;                 // 16*2048*16 = 524288
static const size_t OFF_SORTED  = 1775872;                 // 16*2000*16 = 512000
static const size_t OFF_MASK    = 2287872;                 // 16*2000*32*8 = 8192000

__device__ __forceinline__ unsigned f2u(float f){
  unsigned b = __float_as_uint(f);
  return (b & 0x80000000u) ? ~b : (b | 0x80000000u);
}

// ---------- pass 1 histogram: top 10 bits (8 replicated LDS copies) ----------
#define H1REP 8
#define H1STRIDE 1025
__global__ void k_hist1(const float* __restrict__ cls, unsigned* __restrict__ hist){
  __shared__ unsigned h[H1REP * H1STRIDE];
  int img = blockIdx.y;
  for (int i = threadIdx.x; i < H1REP * H1STRIDE; i += blockDim.x) h[i] = 0;
  __syncthreads();
  const float* p = cls + (size_t)img * NN;
  int stride = gridDim.x * blockDim.x;
  unsigned rep = (threadIdx.x & (H1REP - 1)) * H1STRIDE;
  for (int i = blockIdx.x * blockDim.x + threadIdx.x; i < NN; i += stride)
    atomicAdd(&h[rep + (f2u(p[i]) >> 22)], 1u);
  __syncthreads();
  unsigned* g = hist + img * 1024;
  for (int i = threadIdx.x; i < 1024; i += blockDim.x){
    unsigned v = 0;
    for (int r = 0; r < H1REP; r++) v += h[r * H1STRIDE + i];
    if (v) atomicAdd(&g[i], v);
  }
}

// ---------- generic descending rank-select over a histogram ----------
__global__ void k_scan(const unsigned* __restrict__ hist, int bins,
                       const unsigned* __restrict__ tgt, unsigned K0,
                       unsigned* __restrict__ outBin, unsigned* __restrict__ outNeed){
  int img = blockIdx.x;
  int t = threadIdx.x;
  const unsigned* hh = hist + img * bins;
  unsigned K = tgt ? tgt[img] : K0;
  int per = bins >> 8;
  unsigned s = 0;
  for (int q = 0; q < per; q++) s += hh[bins - 1 - (t * per + q)];
  __shared__ unsigned arr[256];
  arr[t] = s;
  __syncthreads();
  for (int off = 1; off < 256; off <<= 1){
    unsigned v = (t >= off) ? arr[t - off] : 0u;
    __syncthreads();
    arr[t] += v;
    __syncthreads();
  }
  unsigned incl = arr[t], excl = incl - s;
  if (excl < K && K <= incl){
    unsigned c = excl;
    for (int q = 0; q < per; q++){
      int b = bins - 1 - (t * per + q);
      unsigned cnt = hh[b];
      if (c + cnt >= K){ outBin[img] = (unsigned)b; outNeed[img] = K - c; break; }
      c += cnt;
    }
  }
}

// ---------- pass 2 histogram: bits 21..11 within bin b1 ----------
__global__ void k_hist2(const float* __restrict__ cls, const unsigned* __restrict__ b1,
                        unsigned* __restrict__ hist){
  int img = blockIdx.y;
  unsigned bb1 = b1[img];
  const float* p = cls + (size_t)img * NN;
  unsigned* g = hist + img * 2048;
  int stride = gridDim.x * blockDim.x;
  for (int i = blockIdx.x * blockDim.x + threadIdx.x; i < NN; i += stride){
    unsigned u = f2u(p[i]);
    if ((u >> 22) == bb1) atomicAdd(&g[(u >> 11) & 0x7FFu], 1u);
  }
}

// ---------- pass 3 histogram: bits 10..0 within (b1,b2) ----------
__global__ void k_hist3(const float* __restrict__ cls, const unsigned* __restrict__ b1,
                        const unsigned* __restrict__ b2, unsigned* __restrict__ hist){
  int img = blockIdx.y;
  unsigned pref = (b1[img] << 11) | b2[img];
  const float* p = cls + (size_t)img * NN;
  unsigned* g = hist + img * 2048;
  int stride = gridDim.x * blockDim.x;
  for (int i = blockIdx.x * blockDim.x + threadIdx.x; i < NN; i += stride){
    unsigned u = f2u(p[i]);
    if ((u >> 11) == pref) atomicAdd(&g[u & 0x7FFu], 1u);
  }
}

// ---------- compaction: u > T -> cand ; u == T -> eqbuf (LDS-aggregated) ----------
__global__ void k_compact(const float* __restrict__ cls, const unsigned* __restrict__ b1,
                          const unsigned* __restrict__ b2, const unsigned* __restrict__ b3,
                          unsigned* __restrict__ cand, unsigned* __restrict__ candCnt,
                          unsigned* __restrict__ eqbuf, unsigned* __restrict__ eqCnt){
  __shared__ unsigned lc[1024];
  __shared__ unsigned le[256];
  __shared__ unsigned lcn, len_, baseC, baseE;
  int img = blockIdx.y;
  if (threadIdx.x == 0){ lcn = 0; len_ = 0; }
  __syncthreads();
  unsigned T = (b1[img] << 22) | (b2[img] << 11) | b3[img];
  const float* p = cls + (size_t)img * NN;
  int stride = gridDim.x * blockDim.x;
  for (int i = blockIdx.x * blockDim.x + threadIdx.x; i < NN; i += stride){
    unsigned u = f2u(p[i]);
    if (u > T){
      unsigned pos = atomicAdd(&lcn, 1u);
      if (pos < 1024u) lc[pos] = (unsigned)i;
      else { unsigned g = atomicAdd(&candCnt[img], 1u); if (g < 2048u) cand[img * 2048 + g] = (unsigned)i; }
    } else if (u == T){
      unsigned pos = atomicAdd(&len_, 1u);
      if (pos < 256u) le[pos] = (unsigned)i;
      else { unsigned g = atomicAdd(&eqCnt[img], 1u); if (g < 8192u) eqbuf[img * 8192 + g] = (unsigned)i; }
    }
  }
  __syncthreads();
  unsigned nc = lcn < 1024u ? lcn : 1024u;
  unsigned ne = len_ < 256u ? len_ : 256u;
  if (threadIdx.x == 0){
    if (nc) baseC = atomicAdd(&candCnt[img], nc);
    if (ne) baseE = atomicAdd(&eqCnt[img], ne);
  }
  __syncthreads();
  for (unsigned t = threadIdx.x; t < nc; t += blockDim.x){
    unsigned g = baseC + t;
    if (g < 2048u) cand[img * 2048 + g] = lc[t];
  }
  for (unsigned t = threadIdx.x; t < ne; t += blockDim.x){
    unsigned g = baseE + t;
    if (g < 8192u) eqbuf[img * 8192 + g] = le[t];
  }
}

// ---------- resolve exact ties at threshold via rank-selection ----------
// Order within cand[] is irrelevant: the (score, ~index) key fixes final order.
// ec is tiny (exact float duplicates at the threshold); O(ec^2) beats any sort.
__global__ void k_finalize(unsigned* __restrict__ cand, const unsigned* __restrict__ candCnt,
                           const unsigned* __restrict__ eqbuf, const unsigned* __restrict__ eqCnt,
                           const unsigned* __restrict__ need3){
  int img = blockIdx.x, tid = threadIdx.x;
  unsigned need = need3[img];
  unsigned ec = eqCnt[img]; if (ec > 8192u) ec = 8192u;
  unsigned base = candCnt[img];
  const unsigned* eq = eqbuf + img * 8192;
  unsigned* c = cand + img * 2048;
  if (need >= ec){
    for (unsigned t = tid; t < ec; t += 256) if (base + t < 2048u) c[base + t] = eq[t];
    return;
  }
  for (unsigned t = tid; t < ec; t += 256){
    unsigned v = eq[t], r = 0;
    for (unsigned s = 0; s < ec; s++) r += (eq[s] < v) ? 1u : 0u;
    if (r < need && base + r < 2048u) c[base + r] = v;
  }
}

// ---------- decode + clip + validity + key; count valid via wave ballot ----------
__global__ void k_decode(const float* __restrict__ cls, const float* __restrict__ reg,
                         const float* __restrict__ anch, const unsigned* __restrict__ cand,
                         float* __restrict__ boxTmp, ull* __restrict__ keys,
                         unsigned* __restrict__ nvalid){
  int s = blockIdx.x * blockDim.x + threadIdx.x;
  if (s >= NB * 2048) return;
  int img = s >> 11, slot = s & 2047;
  ull key = 0ull;
  float4 box = make_float4(0.f, 0.f, 0.f, 0.f);
  bool counted = false;
  if (slot < PRE){
    unsigned i = cand[img * 2048 + slot];
    if (i < NN){
      size_t gi = (size_t)img * NN + i;
      float4 a = ((const float4*)anch)[gi];
      float4 r = ((const float4*)reg)[gi];
      float sc = cls[gi];
      float aw = a.z - a.x, ah = a.w - a.y;
      float acx = a.x + 0.5f * aw, acy = a.y + 0.5f * ah;
      float pcx = r.x * aw + acx, pcy = r.y * ah + acy;
      float pw = expf(r.z) * aw, ph = expf(r.w) * ah;
      float x1 = pcx - 0.5f * pw, y1 = pcy - 0.5f * ph;
      float x2 = pcx + 0.5f * pw, y2 = pcy + 0.5f * ph;
      x1 = fminf(fmaxf(x1, 0.f), 1333.f); x2 = fminf(fmaxf(x2, 0.f), 1333.f);
      y1 = fminf(fmaxf(y1, 0.f), 800.f);  y2 = fminf(fmaxf(y2, 0.f), 800.f);
      bool valid = ((x2 - x1) >= 0.001f) && ((y2 - y1) >= 0.001f);
      unsigned up = valid ? f2u(sc) : 0u;
      key = ((ull)up << 32) | (ull)(0xFFFFFFFFu - i);   // score desc, index asc
      box = make_float4(x1, y1, x2, y2);
      counted = valid;
    }
  }
  keys[img * 2048 + slot] = key;
  ((float4*)boxTmp)[img * 2048 + slot] = box;
  // one atomic per wave (blocks are 256 = 4 waves, all within one image: 2048 | 256)
  ull bal = __ballot(counted);
  if ((threadIdx.x & 63) == 0 && bal)
    atomicAdd(&nvalid[img], (unsigned)__popcll(bal));
}

// ---------- rank-by-counting sort: rank = #{j : key_j > key_e}; scatter ----------
// Keys are unique (index baked in) => ranks are a permutation of 0..2047.
// The 48 padding slots hold key=0 (global minimum) => real 2000 get ranks 0..1999.
// Uniform j loop => same-address LDS broadcast, conflict-free; 128 blocks.
__global__ __launch_bounds__(256) void k_rank(const ull* __restrict__ keys,
                                              const float* __restrict__ boxTmp,
                                              float* __restrict__ sorted){
  __shared__ ull lk[2048];
  int img = blockIdx.y;
  int e = blockIdx.x * 256 + threadIdx.x;
  for (int t = threadIdx.x; t < 2048; t += 256) lk[t] = keys[img * 2048 + t];
  __syncthreads();
  ull me = lk[e];
  unsigned rank = 0;
  #pragma unroll 8
  for (int j = 0; j < 2048; j++) rank += (lk[j] > me) ? 1u : 0u;
  if (rank < PRE)
    ((float4*)sorted)[img * PRE + rank] = ((const float4*)boxTmp)[img * 2048 + e];
}

// ---------- suppression bitmask, PERMUTED layout: word w bit q <-> j = 32q+w ----------
__global__ __launch_bounds__(512) void k_mask(const float* __restrict__ sorted,
                                              const unsigned* __restrict__ nvalid,
                                              ull* __restrict__ mask, ull* __restrict__ bitmap){
  __shared__ float4 bx[PRE];
  __shared__ float  ar[PRE];
  __shared__ unsigned rowflag[16];
  int img = blockIdx.y, tid = threadIdx.x;
  if (tid < 16) rowflag[tid] = 0;
  for (int i = tid; i < PRE; i += 512){
    float4 b = ((const float4*)sorted)[img * PRE + i];
    bx[i] = b;
    ar[i] = (b.z - b.x) * (b.w - b.y);
  }
  __syncthreads();
  int row = blockIdx.x * 16 + (tid >> 5);
  int w = tid & 31;
  float4 bi = bx[row];
  float ai = ar[row];
  int qlo = (row >= w) ? (((row - w) >> 5) + 1) : 0;
  int qhi = ((PRE - 1 - w) >> 5) + 1;
  ull m = 0;
  for (int q = qlo; q < qhi; q++){
    int j = (q << 5) + w;
    float4 bj = bx[j];
    float xx1 = fmaxf(bi.x, bj.x), yy1 = fmaxf(bi.y, bj.y);
    float xx2 = fminf(bi.z, bj.z), yy2 = fminf(bi.w, bj.w);
    float ww = fmaxf(xx2 - xx1, 0.f), hh = fmaxf(yy2 - yy1, 0.f);
    float inter = ww * hh;
    float uni = ai + ar[j] - inter;
    if (inter / fmaxf(uni, 1e-8f) > 0.7f) m |= (1ull << q);   // exact div (bit-match)
  }
  mask[((size_t)(img * PRE + row)) * 32 + w] = m;
  if (m) atomicOr(&rowflag[tid >> 5], 1u);
  __syncthreads();
  if (tid < 16){
    int r = blockIdx.x * 16 + tid;
    if (rowflag[tid] && r < (int)nvalid[img])
      atomicOr(&bitmap[img * 32 + (r >> 6)], 1ull << (r & 63));
  }
}

// ---------- serial NMS scan (nonzero rows only, permuted masks) + rank/scatter ----------
__global__ __launch_bounds__(256) void k_nms(const ull* __restrict__ mask,
                                             const ull* __restrict__ bitmap,
                                             const unsigned* __restrict__ nvalid,
                                             const float* __restrict__ sorted,
                                             float* __restrict__ out){
  __shared__ unsigned rows[2048];
  __shared__ int mcount;
  __shared__ ull cache[192 * 32];
  __shared__ ull keepP[32];     // permuted keep: word w bit q -> j = 32q+w
  __shared__ ull keepLin[32];   // linear keep:   word w bit b -> i = 64w+b
  __shared__ unsigned cntArr[32], preArr[32];
  int img = blockIdx.x, tid = threadIdx.x;
  int lane = tid & 63, wave = tid >> 6;
  if (tid == 0){
    int m = 0;
    for (int w0 = 0; w0 < 32; w0++){
      ull bits = bitmap[img * 32 + w0];
      while (bits){
        int b = __ffsll(bits) - 1;
        rows[m++] = (unsigned)(w0 * 64 + b);   // ascending i order
        bits &= bits - 1;
      }
    }
    mcount = m;
  }
  __syncthreads();
  int m = mcount;
  ull remv = 0;
  for (int base = 0; base < m; base += 192){
    int cnt = min(192, m - base);
    for (int t = tid; t < cnt * 32; t += 256){
      unsigned rr = rows[base + (t >> 5)];
      cache[t] = mask[((size_t)(img * PRE + rr)) * 32 + (t & 31)];
    }
    __syncthreads();
    if (wave == 0){
      for (int q = 0; q < cnt; q++){
        int i = (int)rows[base + q];
        int wi = i & 31, bi = i >> 5;       // permuted coords of i
        int sup = (lane == wi) && ((remv >> bi) & 1ull);
        if (!__any(sup)){
          if (lane < 32) remv |= cache[(q << 5) + lane];
        }
      }
    }
    __syncthreads();
  }
  int nv = (int)nvalid[img];
  if (wave == 0 && lane < 32){
    int cnt2 = (nv > lane) ? (((nv - 1 - lane) >> 5) + 1) : 0;   // #valid q for this word
    ull vm = (cnt2 >= 64) ? ~0ull : ((1ull << cnt2) - 1ull);
    keepP[lane] = (~remv) & vm;
  }
  __syncthreads();
  if (tid < 32){   // permuted -> linear
    ull lin = 0;
    for (int kk = 0; kk < 64; kk++)
      lin |= ((keepP[kk & 31] >> (2 * tid + (kk >> 5))) & 1ull) << kk;
    keepLin[tid] = lin;
    cntArr[tid] = (unsigned)__popcll(lin);
  }
  __syncthreads();
  if (tid < 32){
    unsigned pre = 0;
    for (int w0 = 0; w0 < tid; w0++) pre += cntArr[w0];
    preArr[tid] = pre;
  }
  __syncthreads();
  for (int i = tid; i < PRE; i += 256){
    int w0 = i >> 6, b = i & 63;
    ull kw = keepLin[w0];
    if ((kw >> b) & 1ull){
      unsigned rank = preArr[w0] + (unsigned)__popcll(kw & ((1ull << b) - 1ull));
      if (rank < POST)
        ((float4*)out)[img * POST + rank] = ((const float4*)sorted)[img * PRE + i];
    }
  }
}

extern "C" void kernel_launch(void* const* d_in, const int* in_sizes, int n_in,
                              void* d_out, int out_size, void* d_ws, size_t ws_size,
                              hipStream_t stream){
  const float* cls  = (const float*)d_in[0];
  const float* reg  = (const float*)d_in[1];
  const float* anch = (const float*)d_in[2];
  float* out = (float*)d_out;
  char* ws = (char*)d_ws;

  unsigned* hist1   = (unsigned*)(ws + OFF_HIST1);
  unsigned* hist2   = (unsigned*)(ws + OFF_HIST2);
  unsigned* hist3   = (unsigned*)(ws + OFF_HIST3);
  unsigned* candCnt = (unsigned*)(ws + OFF_CANDCNT);
  unsigned* eqCnt   = (unsigned*)(ws + OFF_EQCNT);
  ull*      bitmap  = (ull*)     (ws + OFF_BITMAP);
  unsigned* b1      = (unsigned*)(ws + OFF_B1);
  unsigned* need1   = (unsigned*)(ws + OFF_NEED1);
  unsigned* b2      = (unsigned*)(ws + OFF_B2);
  unsigned* need2   = (unsigned*)(ws + OFF_NEED2);
  unsigned* b3      = (unsigned*)(ws + OFF_B3);
  unsigned* need3   = (unsigned*)(ws + OFF_NEED3);
  unsigned* nvalid  = (unsigned*)(ws + OFF_NVALID);
  unsigned* cand    = (unsigned*)(ws + OFF_CAND);
  unsigned* eqbuf   = (unsigned*)(ws + OFF_EQBUF);
  ull*      keys    = (ull*)     (ws + OFF_KEYS);
  float*    boxTmp  = (float*)   (ws + OFF_BOXTMP);
  float*    sorted  = (float*)   (ws + OFF_SORTED);
  ull*      mask    = (ull*)     (ws + OFF_MASK);

  hipMemsetAsync(ws, 0, ZERO_BYTES, stream);
  hipMemsetAsync(d_out, 0, (size_t)out_size * sizeof(float), stream);

  k_hist1<<<dim3(64, NB), 256, 0, stream>>>(cls, hist1);
  k_scan <<<NB, 256, 0, stream>>>(hist1, 1024, (const unsigned*)nullptr, 2000u, b1, need1);
  k_hist2<<<dim3(64, NB), 256, 0, stream>>>(cls, b1, hist2);
  k_scan <<<NB, 256, 0, stream>>>(hist2, 2048, need1, 0u, b2, need2);
  k_hist3<<<dim3(64, NB), 256, 0, stream>>>(cls, b1, b2, hist3);
  k_scan <<<NB, 256, 0, stream>>>(hist3, 2048, need2, 0u, b3, need3);
  k_compact<<<dim3(64, NB), 256, 0, stream>>>(cls, b1, b2, b3, cand, candCnt, eqbuf, eqCnt);
  k_finalize<<<NB, 256, 0, stream>>>(cand, candCnt, eqbuf, eqCnt, need3);
  k_decode<<<(NB * 2048) / 256, 256, 0, stream>>>(cls, reg, anch, cand, boxTmp, keys, nvalid);
  k_rank<<<dim3(8, NB), 256, 0, stream>>>(keys, boxTmp, sorted);
  k_mask<<<dim3(PRE / 16, NB), 512, 0, stream>>>(sorted, nvalid, mask, bitmap);
  k_nms<<<NB, 256, 0, stream>>>(mask, bitmap, nvalid, sorted, out);
}